// Round 2
// baseline (1323.852 us; speedup 1.0000x reference)
//
#include <hip/hip_runtime.h>
#include <math.h>

#define NN 4096
#define FF 128
#define HH 4
#define HIDD 64
#define OUTD 16
#define MASKW (NN / 32)
#define ALPHA 0.2f

// ---------------- pack adjacency into bitmask (2 MB) ----------------
__global__ void pack_mask_kernel(const int* __restrict__ adj, unsigned int* __restrict__ mb) {
    int t = blockIdx.x * 256 + threadIdx.x;  // one thread per adj element
    int v = adj[t] > 0;
    unsigned long long bal = __ballot(v);
    if ((threadIdx.x & 63) == 0) {
        int w = t >> 5;  // element index /32; lane0's t is a multiple of 64 -> w even
        mb[w] = (unsigned int)(bal & 0xffffffffULL);
        mb[w + 1] = (unsigned int)(bal >> 32);
    }
}

// ---------------- projection: Hout[hd][i][d] = sum_f A[i][f] * W[hd][f][d] ----------------
template <int FIN, int D>
__global__ __launch_bounds__(256) void proj_kernel(const float* __restrict__ A,
                                                   const float* __restrict__ W,
                                                   float* __restrict__ Hout) {
    constexpr int TI = 32, TF = 32;
    __shared__ float As[TI][TF + 1];
    __shared__ float Ws[TF][D];
    const int hd = blockIdx.z;
    const int i0 = blockIdx.x * TI;
    const float* Wh = W + (size_t)hd * FIN * D;
    const int t = threadIdx.x;
    const int r = t >> 3;   // 0..31 output row within tile
    const int c8 = t & 7;   // 8 threads per row split D
    constexpr int VD = D / 8;
    float acc[VD];
#pragma unroll
    for (int k = 0; k < VD; k++) acc[k] = 0.f;
    for (int f0 = 0; f0 < FIN; f0 += TF) {
        for (int idx = t; idx < TI * TF; idx += 256) {
            int rr = idx >> 5, cc = idx & 31;
            As[rr][cc] = A[(size_t)(i0 + rr) * FIN + f0 + cc];
        }
        for (int idx = t; idx < TF * D; idx += 256) {
            int rr = idx / D, cc = idx % D;  // D is a power of two -> shifts
            Ws[rr][cc] = Wh[(size_t)(f0 + rr) * D + cc];
        }
        __syncthreads();
#pragma unroll
        for (int f = 0; f < TF; f++) {
            float a = As[r][f];
#pragma unroll
            for (int k = 0; k < VD; k++) acc[k] += a * Ws[f][c8 * VD + k];
        }
        __syncthreads();
    }
    float* op = Hout + ((size_t)hd * NN + i0 + r) * D + c8 * VD;
#pragma unroll
    for (int k = 0; k < VD; k++) op[k] = acc[k];
}

// ---------------- attention scores f1/f2: one wave per (hd,i) ----------------
template <int D>
__global__ __launch_bounds__(256) void fdot_kernel(const float* __restrict__ Hbuf,
                                                   const float* __restrict__ a,
                                                   float* __restrict__ f1,
                                                   float* __restrict__ f2) {
    int w = blockIdx.x * 4 + (threadIdx.x >> 6);  // w = hd*NN + i
    int lane = threadIdx.x & 63;
    int hd = w >> 12;
    const float* hrow = Hbuf + (size_t)w * D;
    const float* ah = a + hd * 2 * D;
    float s1 = 0.f, s2 = 0.f;
    for (int d = lane; d < D; d += 64) {
        float hv = hrow[d];
        s1 += hv * ah[d];
        s2 += hv * ah[D + d];
    }
#pragma unroll
    for (int off = 32; off > 0; off >>= 1) {
        s1 += __shfl_down(s1, off);
        s2 += __shfl_down(s2, off);
    }
    if (lane == 0) {
        f1[w] = s1;
        f2[w] = s2;
    }
}

// ---------------- per-head global max of f2 (stability shift) ----------------
__global__ void gmax_kernel(const float* __restrict__ f2, float* __restrict__ gmax) {
    int hd = blockIdx.x;
    const float* p = f2 + (size_t)hd * NN;
    float m = -1e30f;
    for (int i = threadIdx.x; i < NN; i += 256) m = fmaxf(m, p[i]);
    __shared__ float sm[4];
#pragma unroll
    for (int off = 32; off > 0; off >>= 1) m = fmaxf(m, __shfl_down(m, off));
    if ((threadIdx.x & 63) == 0) sm[threadIdx.x >> 6] = m;
    __syncthreads();
    if (threadIdx.x == 0) gmax[hd] = fmaxf(fmaxf(sm[0], sm[1]), fmaxf(sm[2], sm[3]));
}

// ---------------- masked-softmax aggregation (flash-style, no rescale needed) ----------------
// out[i][col0 + d] = epi( (1/l_i) * sum_j p_ij * H[hd][j][d] ),  p = mask ? exp(e - m_i) : 0
// EPI: 0 = none (layer3), 1 = elu(v + x) (layer1 residual), 2 = elu(v) (layer2)
template <int D, int EPI>
__global__ __launch_bounds__(256) void agg_kernel(const float* __restrict__ Hbuf,
                                                  const float* __restrict__ f1,
                                                  const float* __restrict__ f2,
                                                  const float* __restrict__ gmax,
                                                  const unsigned int* __restrict__ mb,
                                                  const float* __restrict__ xres,
                                                  float* __restrict__ out, int ncols) {
    constexpr int TI = 32, TJ = 64;
    __shared__ __align__(16) float hs[TJ * D];
    __shared__ float ps[TI][TJ + 1];  // +1 pad: unpadded stride-64 rows all hit bank j%32 (32-way)
    __shared__ float f2s[TJ];
    const int hd = blockIdx.z;
    const int i0 = blockIdx.x * TI;
    const float* Hh = Hbuf + (size_t)hd * NN * D;
    const int t = threadIdx.x;
    const int lane = t & 63;
    const int r0 = t >> 6;  // phase-A row base (rows r0+4k, k=0..7)
    float f1v[8], mv[8];
    {
        float gm = gmax[hd];
#pragma unroll
        for (int k = 0; k < 8; k++) {
            float f = f1[hd * NN + i0 + r0 + 4 * k];
            f1v[k] = f;
            float mi = f + gm;
            mv[k] = mi > 0.f ? mi : ALPHA * mi;  // leaky(f1 + max f2) >= all e in row
        }
    }
    constexpr int VD = D / 8;
    const int row = t >> 3;  // phase-B row (8 threads per row)
    const int c8 = t & 7;
    float acc[VD];
#pragma unroll
    for (int k = 0; k < VD; k++) acc[k] = 0.f;
    float lsum = 0.f;

    for (int j0 = 0; j0 < NN; j0 += TJ) {
        // stage h tile (contiguous TJ*D floats) into LDS
        const float* src = Hh + (size_t)j0 * D;
        for (int idx = t * 4; idx < TJ * D; idx += 1024)
            *(float4*)&hs[idx] = *(const float4*)&src[idx];
        if (t < TJ) f2s[t] = f2[hd * NN + j0 + t];
        __syncthreads();
        // phase A: p values, exp computed once per (i,j)
        {
            float f2v = f2s[lane];  // j = lane
#pragma unroll
            for (int k = 0; k < 8; k++) {
                int ri = r0 + 4 * k;
                unsigned int mword = mb[(size_t)(i0 + ri) * MASKW + ((j0 + lane) >> 5)];
                float e = f1v[k] + f2v;
                e = e > 0.f ? e : ALPHA * e;
                float p = ((mword >> (lane & 31)) & 1u) ? __expf(e - mv[k]) : 0.f;
                ps[ri][lane] = p;
            }
        }
        __syncthreads();
        // phase B: acc[d] += p * h[j][d]
        for (int j = 0; j < TJ; j++) {
            float p = ps[row][j];
            lsum += p;
            const float* hrow = &hs[j * D + c8 * VD];
#pragma unroll
            for (int k = 0; k < VD; k++) acc[k] += p * hrow[k];
        }
        __syncthreads();
    }
    float inv = 1.f / lsum;
    size_t obase = (size_t)(i0 + row) * ncols + (size_t)hd * D + c8 * VD;
#pragma unroll
    for (int k = 0; k < VD; k++) {
        float v = acc[k] * inv;
        if (EPI == 1) v += xres[(size_t)(i0 + row) * D + c8 * VD + k];
        if (EPI >= 1) v = v > 0.f ? v : (__expf(v) - 1.f);
        out[obase + k] = v;
    }
}

// ---------------- final: log_softmax(elu(h3)) over 16 cols ----------------
__global__ void final_kernel(const float* __restrict__ h3, float* __restrict__ out) {
    int i = blockIdx.x * 256 + threadIdx.x;
    if (i >= NN) return;
    float v[OUTD];
    float mx = -1e30f;
#pragma unroll
    for (int k = 0; k < OUTD; k++) {
        float e = h3[(size_t)i * OUTD + k];
        e = e > 0.f ? e : (__expf(e) - 1.f);
        v[k] = e;
        mx = fmaxf(mx, e);
    }
    float s = 0.f;
#pragma unroll
    for (int k = 0; k < OUTD; k++) s += __expf(v[k] - mx);
    float ls = logf(s);
#pragma unroll
    for (int k = 0; k < OUTD; k++) out[(size_t)i * OUTD + k] = v[k] - mx - ls;
}

extern "C" void kernel_launch(void* const* d_in, const int* in_sizes, int n_in,
                              void* d_out, int out_size, void* d_ws, size_t ws_size,
                              hipStream_t stream) {
    const float* x = (const float*)d_in[0];
    const int* adj = (const int*)d_in[1];
    const float* W_in = (const float*)d_in[2];
    const float* a_in = (const float*)d_in[3];
    const float* W_hid = (const float*)d_in[4];
    const float* a_hid = (const float*)d_in[5];
    const float* W_out = (const float*)d_in[6];
    const float* a_out = (const float*)d_in[7];
    float* out = (float*)d_out;

    // workspace layout (compacted via aliasing; ~18.3 MB total):
    //   mb   : 2 MB bitmask (lives whole time)
    //   hbuf : 8 MB  -- layer1 h (8 MB); layer2 h uses first 4 MB; layer3 h uses first 256 KB
    //          cat2 (4 MB) aliases hbuf+4MB (layer2 h only occupies first 4 MB; layer3 proj
    //          reads cat2 while writing hbuf[0..256KB) -- disjoint)
    //   cat1 : 8 MB  -- dead after layer-2 proj; h3 (256 KB) aliases its start
    //   f1/f2/gm : small
    char* w = (char*)d_ws;
    unsigned int* mb = (unsigned int*)w;  w += (size_t)NN * MASKW * 4;          // 2 MB
    float* hbuf = (float*)w;              w += (size_t)HH * NN * FF * 4;        // 8 MB
    float* cat1 = (float*)w;              w += (size_t)NN * (HH * FF) * 4;      // 8 MB
    float* f1 = (float*)w;                w += (size_t)HH * NN * 4;
    float* f2 = (float*)w;                w += (size_t)HH * NN * 4;
    float* gm = (float*)w;                w += 256;
    float* cat2 = hbuf + (size_t)HH * NN * HIDD;  // alias: upper half of hbuf
    float* h3 = cat1;                             // alias: cat1 dead by then

    hipLaunchKernelGGL(pack_mask_kernel, dim3(NN * NN / 256), dim3(256), 0, stream, adj, mb);

    // ---- layer 1: Fin=128, D=128, 4 heads, residual+elu, concat -> cat1[N,512]
    hipLaunchKernelGGL((proj_kernel<FF, FF>), dim3(NN / 32, 1, HH), dim3(256), 0, stream, x, W_in, hbuf);
    hipLaunchKernelGGL((fdot_kernel<FF>), dim3(HH * NN / 4), dim3(256), 0, stream, hbuf, a_in, f1, f2);
    hipLaunchKernelGGL(gmax_kernel, dim3(HH), dim3(256), 0, stream, f2, gm);
    hipLaunchKernelGGL((agg_kernel<FF, 1>), dim3(NN / 32, 1, HH), dim3(256), 0, stream,
                       hbuf, f1, f2, gm, mb, x, cat1, HH * FF);

    // ---- layer 2: Fin=512, D=64, 4 heads, elu, concat -> cat2[N,256]
    hipLaunchKernelGGL((proj_kernel<HH * FF, HIDD>), dim3(NN / 32, 1, HH), dim3(256), 0, stream, cat1, W_hid, hbuf);
    hipLaunchKernelGGL((fdot_kernel<HIDD>), dim3(HH * NN / 4), dim3(256), 0, stream, hbuf, a_hid, f1, f2);
    hipLaunchKernelGGL(gmax_kernel, dim3(HH), dim3(256), 0, stream, f2, gm);
    hipLaunchKernelGGL((agg_kernel<HIDD, 2>), dim3(NN / 32, 1, HH), dim3(256), 0, stream,
                       hbuf, f1, f2, gm, mb, (const float*)nullptr, cat2, HH * HIDD);

    // ---- layer 3: Fin=256, D=16, 1 head, no elu inside -> h3[N,16]
    hipLaunchKernelGGL((proj_kernel<HH * HIDD, OUTD>), dim3(NN / 32, 1, 1), dim3(256), 0, stream, cat2, W_out, hbuf);
    hipLaunchKernelGGL((fdot_kernel<OUTD>), dim3(NN / 4), dim3(256), 0, stream, hbuf, a_out, f1, f2);
    hipLaunchKernelGGL(gmax_kernel, dim3(1), dim3(256), 0, stream, f2, gm);
    hipLaunchKernelGGL((agg_kernel<OUTD, 0>), dim3(NN / 32, 1, 1), dim3(256), 0, stream,
                       hbuf, f1, f2, gm, mb, (const float*)nullptr, h3, OUTD);

    hipLaunchKernelGGL(final_kernel, dim3(NN / 256), dim3(256), 0, stream, h3, out);
}

// Round 3
// 718.838 us; speedup vs baseline: 1.8417x; 1.8417x over previous
//
#include <hip/hip_runtime.h>
#include <math.h>

#define NN 4096
#define FF 128
#define HH 4
#define HIDD 64
#define OUTD 16
#define MASKW (NN / 32)
#define ALPHA 0.2f

typedef __attribute__((ext_vector_type(8))) short short8;
typedef __attribute__((ext_vector_type(4))) float f32x4;

__device__ __forceinline__ ushort f2bf(float f) {  // RNE f32->bf16 (f >= 0 here, no NaN)
    unsigned u = __float_as_uint(f);
    return (ushort)((u + 0x7fffu + ((u >> 16) & 1u)) >> 16);
}

// ---------------- pack adjacency into bitmask (2 MB) ----------------
__global__ void pack_mask_kernel(const int* __restrict__ adj, unsigned int* __restrict__ mb) {
    int t = blockIdx.x * 256 + threadIdx.x;
    int v = adj[t] > 0;
    unsigned long long bal = __ballot(v);
    if ((threadIdx.x & 63) == 0) {
        int w = t >> 5;
        mb[w] = (unsigned int)(bal & 0xffffffffULL);
        mb[w + 1] = (unsigned int)(bal >> 32);
    }
}

// ---------------- projection + fused f1/f2: h bf16 out, scores fp32 ----------------
// Hb[hd][i][d] = sum_f A[i][f] * W[hd][f][d]  (bf16); f1/f2[hd][i] = h . a1/a2 (fp32)
template <int FIN, int D>
__global__ __launch_bounds__(256) void proj_kernel(const float* __restrict__ A,
                                                   const float* __restrict__ W,
                                                   const float* __restrict__ av,
                                                   ushort* __restrict__ Hb,
                                                   float* __restrict__ f1,
                                                   float* __restrict__ f2) {
    constexpr int TI = 32, TF = 32;
    __shared__ float As[TI][TF + 1];
    __shared__ float Ws[TF][D];
    const int hd = blockIdx.z;
    const int i0 = blockIdx.x * TI;
    const float* Wh = W + (size_t)hd * FIN * D;
    const int t = threadIdx.x;
    const int r = t >> 3;   // output row within tile
    const int c8 = t & 7;   // 8 threads per row split D
    constexpr int VD = D / 8;
    float acc[VD];
#pragma unroll
    for (int k = 0; k < VD; k++) acc[k] = 0.f;
    for (int f0 = 0; f0 < FIN; f0 += TF) {
        for (int idx = t; idx < TI * TF; idx += 256) {
            int rr = idx >> 5, cc = idx & 31;
            As[rr][cc] = A[(size_t)(i0 + rr) * FIN + f0 + cc];
        }
        for (int idx = t; idx < TF * D; idx += 256) {
            int rr = idx / D, cc = idx % D;
            Ws[rr][cc] = Wh[(size_t)(f0 + rr) * D + cc];
        }
        __syncthreads();
#pragma unroll
        for (int f = 0; f < TF; f++) {
            float a = As[r][f];
#pragma unroll
            for (int k = 0; k < VD; k++) acc[k] += a * Ws[f][c8 * VD + k];
        }
        __syncthreads();
    }
    // fused attention score dots (fp32): f1 = h.a[:D], f2 = h.a[D:]
    {
        const float* ah = av + hd * 2 * D;
        float s1 = 0.f, s2 = 0.f;
#pragma unroll
        for (int k = 0; k < VD; k++) {
            float hv = acc[k];
            s1 += hv * ah[c8 * VD + k];
            s2 += hv * ah[D + c8 * VD + k];
        }
#pragma unroll
        for (int o = 1; o < 8; o <<= 1) {  // reduce across the 8 lanes of this row
            s1 += __shfl_xor(s1, o);
            s2 += __shfl_xor(s2, o);
        }
        if (c8 == 0) {
            f1[hd * NN + i0 + r] = s1;
            f2[hd * NN + i0 + r] = s2;
        }
    }
    // bf16 store, packed pairs
    ushort* op = Hb + ((size_t)hd * NN + i0 + r) * D + c8 * VD;
#pragma unroll
    for (int k = 0; k < VD; k += 2) {
        unsigned pk = (unsigned)f2bf(acc[k]) | ((unsigned)f2bf(acc[k + 1]) << 16);
        *(unsigned*)&op[k] = pk;
    }
}

// ---------------- per-head global max of f2 (stability shift) ----------------
__global__ void gmax_kernel(const float* __restrict__ f2, float* __restrict__ gmax) {
    int hd = blockIdx.x;
    const float* p = f2 + (size_t)hd * NN;
    float m = -1e30f;
    for (int i = threadIdx.x; i < NN; i += 256) m = fmaxf(m, p[i]);
    __shared__ float sm[4];
#pragma unroll
    for (int off = 32; off > 0; off >>= 1) m = fmaxf(m, __shfl_down(m, off));
    if ((threadIdx.x & 63) == 0) sm[threadIdx.x >> 6] = m;
    __syncthreads();
    if (threadIdx.x == 0) gmax[hd] = fmaxf(fmaxf(sm[0], sm[1]), fmaxf(sm[2], sm[3]));
}

// ---------------- transpose h: [hd][N][D] bf16 -> [hd][D][N] bf16 ----------------
__global__ __launch_bounds__(256) void transpose_kernel(const ushort* __restrict__ in,
                                                        ushort* __restrict__ out, int D) {
    __shared__ ushort ts[32][33];
    const int hd = blockIdx.z;
    in += (size_t)hd * NN * D;
    out += (size_t)hd * D * NN;
    const int j0 = blockIdx.x * 32, d0 = blockIdx.y * 32;
    const int tx = threadIdx.x & 31, ty = threadIdx.x >> 5;
#pragma unroll
    for (int k = 0; k < 4; k++) {
        int row = ty + 8 * k;
        if (d0 + tx < D) ts[row][tx] = in[(size_t)(j0 + row) * D + d0 + tx];
    }
    __syncthreads();
#pragma unroll
    for (int k = 0; k < 4; k++) {
        int dr = ty + 8 * k;
        if (d0 + dr < D) out[(size_t)(d0 + dr) * NN + j0 + tx] = ts[tx][dr];
    }
}

// ---------------- MFMA flash aggregation ----------------
// out[i][hd*D + d] = epi( (1/l_i) * sum_j p_ij * h[j][d] ),  p = mask ? exp(leaky(f1+f2) - m_i) : 0
// A-frag (p) built in registers: lane holds rows m=lane&15, k = (lane>>4)*8 + t (8 consecutive j).
// B-frag read from hT[d][j] (= B^T layout) as contiguous 16B.
// NW waves split the j range (NW>1 requires D==16).
template <int D, int EPI, int NW>
__global__ __launch_bounds__(NW * 64) void agg_mfma_kernel(const ushort* __restrict__ hT,
                                                           const float* __restrict__ f1,
                                                           const float* __restrict__ f2,
                                                           const float* __restrict__ gmax,
                                                           const unsigned int* __restrict__ mb,
                                                           const float* __restrict__ xres,
                                                           float* __restrict__ out, int ncols) {
    constexpr int NT = D / 16;
    static_assert(NW == 1 || NT == 1, "j-split only for single-tile D");
    const int hd = blockIdx.z;
    const int i0 = blockIdx.x * 16;
    const int w = threadIdx.x >> 6;
    const int lane = threadIdx.x & 63;
    const int ln = lane & 15;
    const int g = lane >> 4;
    const int g8 = g * 8;
    const ushort* hTh = hT + (size_t)hd * D * NN;
    const float f1v = f1[hd * NN + i0 + ln];
    const float gm = gmax[hd];
    float mi = f1v + gm;
    mi = fmaxf(mi, ALPHA * mi);  // leaky(f1 + max f2) >= every e in this row
    f32x4 acc[NT];
#pragma unroll
    for (int n = 0; n < NT; n++) acc[n] = (f32x4)(0.f);
    float lsum = 0.f;
    const float* f2h = f2 + hd * NN;
    const unsigned* mrow = mb + (size_t)(i0 + ln) * MASKW;
    const int jbeg = w * (NN / NW), jend = jbeg + NN / NW;

    for (int j0 = jbeg; j0 < jend; j0 += 32) {
        unsigned bits = (mrow[j0 >> 5] >> g8) & 0xffu;
        f32x4 fA = *(const f32x4*)&f2h[j0 + g8];
        f32x4 fB = *(const f32x4*)&f2h[j0 + g8 + 4];
        short8 aF;
#pragma unroll
        for (int t = 0; t < 8; t++) {
            float f2t = (t < 4) ? fA[t] : fB[t - 4];
            float e = f1v + f2t;
            e = fmaxf(e, ALPHA * e);
            float p = ((bits >> t) & 1u) ? __expf(e - mi) : 0.f;
            ushort pb = f2bf(p);
            aF[t] = (short)pb;
            lsum += __uint_as_float((unsigned)pb << 16);  // sum the SAME rounded p the MFMA sees
        }
#pragma unroll
        for (int n = 0; n < NT; n++) {
            short8 bF = *(const short8*)&hTh[(size_t)(n * 16 + ln) * NN + j0 + g8];
            acc[n] = __builtin_amdgcn_mfma_f32_16x16x32_bf16(aF, bF, acc[n], 0, 0, 0);
        }
    }
    // row totals: sum over the 4 k-groups -> every lane holds total for row ln
    lsum += __shfl_xor(lsum, 16);
    lsum += __shfl_xor(lsum, 32);

    float accF[NT][4];
    float ltot;
    __shared__ float accL[NW][16][17];
    __shared__ float lsL[NW][16];
    if constexpr (NW == 1) {
#pragma unroll
        for (int n = 0; n < NT; n++)
#pragma unroll
            for (int r = 0; r < 4; r++) accF[n][r] = acc[n][r];
        ltot = lsum;
    } else {
#pragma unroll
        for (int r = 0; r < 4; r++) accL[w][g * 4 + r][ln] = acc[0][r];
        if (lane < 16) lsL[w][lane] = lsum;
        __syncthreads();
        if (w != 0) return;
#pragma unroll
        for (int r = 0; r < 4; r++) {
            float s = 0.f;
            for (int ww = 0; ww < NW; ww++) s += accL[ww][g * 4 + r][ln];
            accF[0][r] = s;
        }
        float s = 0.f;
        for (int ww = 0; ww < NW; ww++) s += lsL[ww][ln];
        ltot = s;
    }
    const float linv = 1.f / ltot;  // valid for row ln
#pragma unroll
    for (int n = 0; n < NT; n++) {
#pragma unroll
        for (int r = 0; r < 4; r++) {
            float invr = __shfl(linv, (g << 2) + r);  // inv for C-row (lane>>4)*4+r
            float v = accF[n][r] * invr;
            int row = i0 + g * 4 + r;
            int col = n * 16 + ln;
            if (EPI == 1) v += xres[(size_t)row * D + col];
            if (EPI >= 1) v = v > 0.f ? v : (__expf(v) - 1.f);
            out[(size_t)row * ncols + hd * D + col] = v;
        }
    }
}

// ---------------- final: log_softmax(elu(h3)) over 16 cols ----------------
__global__ void final_kernel(const float* __restrict__ h3, float* __restrict__ out) {
    int i = blockIdx.x * 256 + threadIdx.x;
    if (i >= NN) return;
    float v[OUTD];
    float mx = -1e30f;
#pragma unroll
    for (int k = 0; k < OUTD; k++) {
        float e = h3[(size_t)i * OUTD + k];
        e = e > 0.f ? e : (__expf(e) - 1.f);
        v[k] = e;
        mx = fmaxf(mx, e);
    }
    float s = 0.f;
#pragma unroll
    for (int k = 0; k < OUTD; k++) s += __expf(v[k] - mx);
    float ls = logf(s);
#pragma unroll
    for (int k = 0; k < OUTD; k++) out[(size_t)i * OUTD + k] = v[k] - mx - ls;
}

extern "C" void kernel_launch(void* const* d_in, const int* in_sizes, int n_in,
                              void* d_out, int out_size, void* d_ws, size_t ws_size,
                              hipStream_t stream) {
    const float* x = (const float*)d_in[0];
    const int* adj = (const int*)d_in[1];
    const float* W_in = (const float*)d_in[2];
    const float* a_in = (const float*)d_in[3];
    const float* W_hid = (const float*)d_in[4];
    const float* a_hid = (const float*)d_in[5];
    const float* W_out = (const float*)d_in[6];
    const float* a_out = (const float*)d_in[7];
    float* out = (float*)d_out;

    // workspace (~18.4 MB, same proven footprint as r2):
    //   mb 2MB | hb16 4MB (bf16 h, max layer1) | hT 4MB (bf16 h^T) | cat1 8MB fp32 | f1/f2/gm/h3
    //   cat2 aliases cat1[0..4MB) (cat1 dead after proj2 reads it; agg2 writes cat2 after)
    char* w = (char*)d_ws;
    unsigned int* mb = (unsigned int*)w;  w += (size_t)NN * MASKW * 4;            // 2 MB
    ushort* hb16 = (ushort*)w;            w += (size_t)HH * NN * FF * 2;          // 4 MB
    ushort* hT = (ushort*)w;              w += (size_t)HH * NN * FF * 2;          // 4 MB
    float* cat1 = (float*)w;              w += (size_t)NN * (HH * FF) * 4;        // 8 MB
    float* f1 = (float*)w;                w += (size_t)HH * NN * 4;
    float* f2 = (float*)w;                w += (size_t)HH * NN * 4;
    float* gm = (float*)w;                w += 256;
    float* h3 = (float*)w;                w += (size_t)NN * OUTD * 4;             // 256 KB
    float* cat2 = cat1;                                                           // alias (see above)

    hipLaunchKernelGGL(pack_mask_kernel, dim3(NN * NN / 256), dim3(256), 0, stream, adj, mb);

    // ---- layer 1: Fin=128, D=128, 4 heads, residual+elu, concat -> cat1[N,512]
    hipLaunchKernelGGL((proj_kernel<FF, FF>), dim3(NN / 32, 1, HH), dim3(256), 0, stream,
                       x, W_in, a_in, hb16, f1, f2);
    hipLaunchKernelGGL(gmax_kernel, dim3(HH), dim3(256), 0, stream, f2, gm);
    hipLaunchKernelGGL(transpose_kernel, dim3(NN / 32, FF / 32, HH), dim3(256), 0, stream, hb16, hT, FF);
    hipLaunchKernelGGL((agg_mfma_kernel<FF, 1, 1>), dim3(NN / 16, 1, HH), dim3(64), 0, stream,
                       hT, f1, f2, gm, mb, x, cat1, HH * FF);

    // ---- layer 2: Fin=512, D=64, 4 heads, elu, concat -> cat2[N,256]
    hipLaunchKernelGGL((proj_kernel<HH * FF, HIDD>), dim3(NN / 32, 1, HH), dim3(256), 0, stream,
                       cat1, W_hid, a_hid, hb16, f1, f2);
    hipLaunchKernelGGL(gmax_kernel, dim3(HH), dim3(256), 0, stream, f2, gm);
    hipLaunchKernelGGL(transpose_kernel, dim3(NN / 32, HIDD / 32, HH), dim3(256), 0, stream, hb16, hT, HIDD);
    hipLaunchKernelGGL((agg_mfma_kernel<HIDD, 2, 1>), dim3(NN / 16, 1, HH), dim3(64), 0, stream,
                       hT, f1, f2, gm, mb, (const float*)nullptr, cat2, HH * HIDD);

    // ---- layer 3: Fin=256, D=16, 1 head, no elu inside -> h3[N,16]
    hipLaunchKernelGGL((proj_kernel<HH * HIDD, OUTD>), dim3(NN / 32, 1, 1), dim3(256), 0, stream,
                       cat2, W_out, a_out, hb16, f1, f2);
    hipLaunchKernelGGL(gmax_kernel, dim3(1), dim3(256), 0, stream, f2, gm);
    hipLaunchKernelGGL(transpose_kernel, dim3(NN / 32, 1, 1), dim3(256), 0, stream, hb16, hT, OUTD);
    hipLaunchKernelGGL((agg_mfma_kernel<OUTD, 0, 4>), dim3(NN / 16, 1, 1), dim3(256), 0, stream,
                       hT, f1, f2, gm, mb, (const float*)nullptr, h3, OUTD);

    hipLaunchKernelGGL(final_kernel, dim3(NN / 256), dim3(256), 0, stream, h3, out);
}

// Round 4
// 449.208 us; speedup vs baseline: 2.9471x; 1.6002x over previous
//
#include <hip/hip_runtime.h>
#include <math.h>

#define NN 4096
#define FF 128
#define HH 4
#define HIDD 64
#define OUTD 16
#define MASKW (NN / 32)
#define ALPHA 0.2f

typedef __attribute__((ext_vector_type(8))) short short8;
typedef __attribute__((ext_vector_type(4))) float f32x4;

__device__ __forceinline__ ushort f2bf(float f) {  // RNE f32->bf16 (f >= 0 here, no NaN)
    unsigned u = __float_as_uint(f);
    return (ushort)((u + 0x7fffu + ((u >> 16) & 1u)) >> 16);
}

// ---------------- pack adjacency into bitmask (2 MB) ----------------
__global__ void pack_mask_kernel(const int* __restrict__ adj, unsigned int* __restrict__ mb) {
    int t = blockIdx.x * 256 + threadIdx.x;
    int v = adj[t] > 0;
    unsigned long long bal = __ballot(v);
    if ((threadIdx.x & 63) == 0) {
        int w = t >> 5;
        mb[w] = (unsigned int)(bal & 0xffffffffULL);
        mb[w + 1] = (unsigned int)(bal >> 32);
    }
}

// ---------------- projection + fused f1/f2: h bf16 out, scores fp32 ----------------
template <int FIN, int D>
__global__ __launch_bounds__(256) void proj_kernel(const float* __restrict__ A,
                                                   const float* __restrict__ W,
                                                   const float* __restrict__ av,
                                                   ushort* __restrict__ Hb,
                                                   float* __restrict__ f1,
                                                   float* __restrict__ f2) {
    constexpr int TI = 32, TF = 32;
    __shared__ float As[TI][TF + 1];
    __shared__ float Ws[TF][D];
    const int hd = blockIdx.z;
    const int i0 = blockIdx.x * TI;
    const float* Wh = W + (size_t)hd * FIN * D;
    const int t = threadIdx.x;
    const int r = t >> 3;
    const int c8 = t & 7;
    constexpr int VD = D / 8;
    float acc[VD];
#pragma unroll
    for (int k = 0; k < VD; k++) acc[k] = 0.f;
    for (int f0 = 0; f0 < FIN; f0 += TF) {
        for (int idx = t; idx < TI * TF; idx += 256) {
            int rr = idx >> 5, cc = idx & 31;
            As[rr][cc] = A[(size_t)(i0 + rr) * FIN + f0 + cc];
        }
        for (int idx = t; idx < TF * D; idx += 256) {
            int rr = idx / D, cc = idx % D;
            Ws[rr][cc] = Wh[(size_t)(f0 + rr) * D + cc];
        }
        __syncthreads();
#pragma unroll
        for (int f = 0; f < TF; f++) {
            float a = As[r][f];
#pragma unroll
            for (int k = 0; k < VD; k++) acc[k] += a * Ws[f][c8 * VD + k];
        }
        __syncthreads();
    }
    {
        const float* ah = av + hd * 2 * D;
        float s1 = 0.f, s2 = 0.f;
#pragma unroll
        for (int k = 0; k < VD; k++) {
            float hv = acc[k];
            s1 += hv * ah[c8 * VD + k];
            s2 += hv * ah[D + c8 * VD + k];
        }
#pragma unroll
        for (int o = 1; o < 8; o <<= 1) {
            s1 += __shfl_xor(s1, o);
            s2 += __shfl_xor(s2, o);
        }
        if (c8 == 0) {
            f1[hd * NN + i0 + r] = s1;
            f2[hd * NN + i0 + r] = s2;
        }
    }
    ushort* op = Hb + ((size_t)hd * NN + i0 + r) * D + c8 * VD;
#pragma unroll
    for (int k = 0; k < VD; k += 2) {
        unsigned pk = (unsigned)f2bf(acc[k]) | ((unsigned)f2bf(acc[k + 1]) << 16);
        *(unsigned*)&op[k] = pk;
    }
}

// ---------------- per-head global max of f2 ----------------
__global__ void gmax_kernel(const float* __restrict__ f2, float* __restrict__ gmax) {
    int hd = blockIdx.x;
    const float* p = f2 + (size_t)hd * NN;
    float m = -1e30f;
    for (int i = threadIdx.x; i < NN; i += 256) m = fmaxf(m, p[i]);
    __shared__ float sm[4];
#pragma unroll
    for (int off = 32; off > 0; off >>= 1) m = fmaxf(m, __shfl_down(m, off));
    if ((threadIdx.x & 63) == 0) sm[threadIdx.x >> 6] = m;
    __syncthreads();
    if (threadIdx.x == 0) gmax[hd] = fmaxf(fmaxf(sm[0], sm[1]), fmaxf(sm[2], sm[3]));
}

// ---------------- transpose h: [hd][N][D] bf16 -> [hd][D][N] bf16 ----------------
__global__ __launch_bounds__(256) void transpose_kernel(const ushort* __restrict__ in,
                                                        ushort* __restrict__ out, int D) {
    __shared__ ushort ts[32][33];
    const int hd = blockIdx.z;
    in += (size_t)hd * NN * D;
    out += (size_t)hd * D * NN;
    const int j0 = blockIdx.x * 32, d0 = blockIdx.y * 32;
    const int tx = threadIdx.x & 31, ty = threadIdx.x >> 5;
#pragma unroll
    for (int k = 0; k < 4; k++) {
        int row = ty + 8 * k;
        if (d0 + tx < D) ts[row][tx] = in[(size_t)(j0 + row) * D + d0 + tx];
    }
    __syncthreads();
#pragma unroll
    for (int k = 0; k < 4; k++) {
        int dr = ty + 8 * k;
        if (d0 + dr < D) out[(size_t)(d0 + dr) * NN + j0 + tx] = ts[tx][dr];
    }
}

// ---------------- staged multi-wave MFMA aggregation (L1/L2) ----------------
// Block = 4 waves; wave w owns rows i0 = blockIdx.x*64 + w*16. Per j-step of 32,
// the block stages hT[:, j0:j0+32] into LDS (reg double-buffered), each wave
// builds its p A-frag in registers (truncated bf16; lsum from same bits),
// reads B-frags from LDS, accumulates D/16 MFMA tiles.
template <int D, int EPI>
__global__ __launch_bounds__(256) void agg2_kernel(const ushort* __restrict__ hT,
                                                   const float* __restrict__ f1,
                                                   const float* __restrict__ f2,
                                                   const float* __restrict__ gmax,
                                                   const unsigned int* __restrict__ mb,
                                                   const float* __restrict__ xres,
                                                   float* __restrict__ out, int ncols) {
    constexpr int NT = D / 16;       // MFMA col-tiles
    constexpr int NC = D / 64;       // staging chunks (16B) per thread
    __shared__ ushort hs[D][40];     // pad 32->40: b128 reads <=2-way bank aliased
    const int hd = blockIdx.z;
    const int t = threadIdx.x;
    const int w = t >> 6;
    const int lane = t & 63;
    const int ln = lane & 15;
    const int g = lane >> 4;
    const int g8 = g * 8;
    const int i0 = blockIdx.x * 64 + w * 16;
    const ushort* hTh = hT + (size_t)hd * D * NN;

    const float f1v = f1[hd * NN + i0 + ln];
    const float gm = gmax[hd];
    float mi = f1v + gm;
    mi = fmaxf(mi, ALPHA * mi);
    const float L2E = 1.442695040888963f;
    const float cexp = -mi * L2E;  // p = exp2(e*L2E + cexp)

    f32x4 acc[NT];
#pragma unroll
    for (int n = 0; n < NT; n++) acc[n] = (f32x4)(0.f);
    float lsum = 0.f;
    const float* f2h = f2 + hd * NN;
    const unsigned* mrow = mb + (size_t)(i0 + ln) * MASKW;

    // staging chunk coords for this thread (chunk c -> row c>>2, 16B part c&3)
    int srow[NC], scol[NC];
#pragma unroll
    for (int c = 0; c < NC; c++) {
        int ch = t + c * 256;
        srow[c] = ch >> 2;
        scol[c] = (ch & 3) * 8;
    }
    uint4 st[NC];
#pragma unroll
    for (int c = 0; c < NC; c++)
        st[c] = *(const uint4*)&hTh[(size_t)srow[c] * NN + scol[c]];
    unsigned mw = mrow[0];
    f32x4 fA = *(const f32x4*)&f2h[g8];
    f32x4 fB = *(const f32x4*)&f2h[g8 + 4];

    for (int j0 = 0; j0 < NN; j0 += 32) {
        __syncthreads();  // previous tile fully consumed
#pragma unroll
        for (int c = 0; c < NC; c++) *(uint4*)&hs[srow[c]][scol[c]] = st[c];
        __syncthreads();  // tile visible
        const bool more = (j0 + 32) < NN;
        // prefetch next staging tile + next A-inputs
        if (more) {
#pragma unroll
            for (int c = 0; c < NC; c++)
                st[c] = *(const uint4*)&hTh[(size_t)srow[c] * NN + j0 + 32 + scol[c]];
        }
        unsigned bits = (mw >> g8) & 0xffu;
        f32x4 cA = fA, cB = fB;
        if (more) {
            mw = mrow[(j0 + 32) >> 5];
            fA = *(const f32x4*)&f2h[j0 + 32 + g8];
            fB = *(const f32x4*)&f2h[j0 + 32 + g8 + 4];
        }
        // build A-frag (truncated bf16), lsum from the same truncated bits
        unsigned au[4];
#pragma unroll
        for (int tp = 0; tp < 4; tp++) {
            unsigned pu[2];
#pragma unroll
            for (int q = 0; q < 2; q++) {
                int tt = tp * 2 + q;
                float f2t = (tt < 4) ? cA[tt] : cB[tt - 4];
                float e = f1v + f2t;
                e = fmaxf(e, ALPHA * e);
                float p = ((bits >> tt) & 1u) ? __builtin_amdgcn_exp2f(e * L2E + cexp) : 0.f;
                pu[q] = __float_as_uint(p) & 0xffff0000u;
                lsum += __uint_as_float(pu[q]);
            }
            au[tp] = (pu[0] >> 16) | pu[1];
        }
        union { unsigned u[4]; short8 s; } aF;
#pragma unroll
        for (int q = 0; q < 4; q++) aF.u[q] = au[q];
#pragma unroll
        for (int n = 0; n < NT; n++) {
            short8 bF = *(const short8*)&hs[n * 16 + ln][g8];
            acc[n] = __builtin_amdgcn_mfma_f32_16x16x32_bf16(aF.s, bF, acc[n], 0, 0, 0);
        }
    }
    lsum += __shfl_xor(lsum, 16);
    lsum += __shfl_xor(lsum, 32);
    const float linv = 1.f / lsum;  // row ln total
#pragma unroll
    for (int n = 0; n < NT; n++) {
#pragma unroll
        for (int r = 0; r < 4; r++) {
            float invr = __shfl(linv, (g << 2) + r);
            float v = acc[n][r] * invr;
            int row = i0 + g * 4 + r;
            int col = n * 16 + ln;
            if (EPI == 1) v += xres[(size_t)row * D + col];
            if (EPI >= 1) v = v > 0.f ? v : (__expf(v) - 1.f);
            out[(size_t)row * ncols + hd * D + col] = v;
        }
    }
}

// ---------------- single-wave MFMA aggregation with j-split (L3, D=16) ----------------
template <int D, int EPI, int NW>
__global__ __launch_bounds__(NW * 64) void agg_mfma_kernel(const ushort* __restrict__ hT,
                                                           const float* __restrict__ f1,
                                                           const float* __restrict__ f2,
                                                           const float* __restrict__ gmax,
                                                           const unsigned int* __restrict__ mb,
                                                           const float* __restrict__ xres,
                                                           float* __restrict__ out, int ncols) {
    constexpr int NT = D / 16;
    static_assert(NW == 1 || NT == 1, "j-split only for single-tile D");
    const int hd = blockIdx.z;
    const int i0 = blockIdx.x * 16;
    const int w = threadIdx.x >> 6;
    const int lane = threadIdx.x & 63;
    const int ln = lane & 15;
    const int g = lane >> 4;
    const int g8 = g * 8;
    const ushort* hTh = hT + (size_t)hd * D * NN;
    const float f1v = f1[hd * NN + i0 + ln];
    const float gm = gmax[hd];
    float mi = f1v + gm;
    mi = fmaxf(mi, ALPHA * mi);
    f32x4 acc[NT];
#pragma unroll
    for (int n = 0; n < NT; n++) acc[n] = (f32x4)(0.f);
    float lsum = 0.f;
    const float* f2h = f2 + hd * NN;
    const unsigned* mrow = mb + (size_t)(i0 + ln) * MASKW;
    const int jbeg = w * (NN / NW), jend = jbeg + NN / NW;

    for (int j0 = jbeg; j0 < jend; j0 += 32) {
        unsigned bits = (mrow[j0 >> 5] >> g8) & 0xffu;
        f32x4 fA = *(const f32x4*)&f2h[j0 + g8];
        f32x4 fB = *(const f32x4*)&f2h[j0 + g8 + 4];
        short8 aF;
#pragma unroll
        for (int t = 0; t < 8; t++) {
            float f2t = (t < 4) ? fA[t] : fB[t - 4];
            float e = f1v + f2t;
            e = fmaxf(e, ALPHA * e);
            float p = ((bits >> t) & 1u) ? __expf(e - mi) : 0.f;
            ushort pb = f2bf(p);
            aF[t] = (short)pb;
            lsum += __uint_as_float((unsigned)pb << 16);
        }
#pragma unroll
        for (int n = 0; n < NT; n++) {
            short8 bF = *(const short8*)&hTh[(size_t)(n * 16 + ln) * NN + j0 + g8];
            acc[n] = __builtin_amdgcn_mfma_f32_16x16x32_bf16(aF, bF, acc[n], 0, 0, 0);
        }
    }
    lsum += __shfl_xor(lsum, 16);
    lsum += __shfl_xor(lsum, 32);

    float accF[NT][4];
    float ltot;
    __shared__ float accL[NW][16][17];
    __shared__ float lsL[NW][16];
    if constexpr (NW == 1) {
#pragma unroll
        for (int n = 0; n < NT; n++)
#pragma unroll
            for (int r = 0; r < 4; r++) accF[n][r] = acc[n][r];
        ltot = lsum;
    } else {
#pragma unroll
        for (int r = 0; r < 4; r++) accL[w][g * 4 + r][ln] = acc[0][r];
        if (lane < 16) lsL[w][lane] = lsum;
        __syncthreads();
        if (w != 0) return;
#pragma unroll
        for (int r = 0; r < 4; r++) {
            float s = 0.f;
            for (int ww = 0; ww < NW; ww++) s += accL[ww][g * 4 + r][ln];
            accF[0][r] = s;
        }
        float s = 0.f;
        for (int ww = 0; ww < NW; ww++) s += lsL[ww][ln];
        ltot = s;
    }
    const float linv = 1.f / ltot;
#pragma unroll
    for (int n = 0; n < NT; n++) {
#pragma unroll
        for (int r = 0; r < 4; r++) {
            float invr = __shfl(linv, (g << 2) + r);
            float v = accF[n][r] * invr;
            int row = i0 + g * 4 + r;
            int col = n * 16 + ln;
            if (EPI == 1) v += xres[(size_t)row * D + col];
            if (EPI >= 1) v = v > 0.f ? v : (__expf(v) - 1.f);
            out[(size_t)row * ncols + hd * D + col] = v;
        }
    }
}

// ---------------- final: log_softmax(elu(h3)) over 16 cols ----------------
__global__ void final_kernel(const float* __restrict__ h3, float* __restrict__ out) {
    int i = blockIdx.x * 256 + threadIdx.x;
    if (i >= NN) return;
    float v[OUTD];
    float mx = -1e30f;
#pragma unroll
    for (int k = 0; k < OUTD; k++) {
        float e = h3[(size_t)i * OUTD + k];
        e = e > 0.f ? e : (__expf(e) - 1.f);
        v[k] = e;
        mx = fmaxf(mx, e);
    }
    float s = 0.f;
#pragma unroll
    for (int k = 0; k < OUTD; k++) s += __expf(v[k] - mx);
    float ls = logf(s);
#pragma unroll
    for (int k = 0; k < OUTD; k++) out[(size_t)i * OUTD + k] = v[k] - mx - ls;
}

extern "C" void kernel_launch(void* const* d_in, const int* in_sizes, int n_in,
                              void* d_out, int out_size, void* d_ws, size_t ws_size,
                              hipStream_t stream) {
    const float* x = (const float*)d_in[0];
    const int* adj = (const int*)d_in[1];
    const float* W_in = (const float*)d_in[2];
    const float* a_in = (const float*)d_in[3];
    const float* W_hid = (const float*)d_in[4];
    const float* a_hid = (const float*)d_in[5];
    const float* W_out = (const float*)d_in[6];
    const float* a_out = (const float*)d_in[7];
    float* out = (float*)d_out;

    char* w = (char*)d_ws;
    unsigned int* mb = (unsigned int*)w;  w += (size_t)NN * MASKW * 4;            // 2 MB
    ushort* hb16 = (ushort*)w;            w += (size_t)HH * NN * FF * 2;          // 4 MB
    ushort* hT = (ushort*)w;              w += (size_t)HH * NN * FF * 2;          // 4 MB
    float* cat1 = (float*)w;              w += (size_t)NN * (HH * FF) * 4;        // 8 MB
    float* f1 = (float*)w;                w += (size_t)HH * NN * 4;
    float* f2 = (float*)w;                w += (size_t)HH * NN * 4;
    float* gm = (float*)w;                w += 256;
    float* h3 = (float*)w;                w += (size_t)NN * OUTD * 4;             // 256 KB
    float* cat2 = cat1;                                                           // alias

    hipLaunchKernelGGL(pack_mask_kernel, dim3(NN * NN / 256), dim3(256), 0, stream, adj, mb);

    // ---- layer 1: Fin=128, D=128, 4 heads, residual+elu, concat -> cat1[N,512]
    hipLaunchKernelGGL((proj_kernel<FF, FF>), dim3(NN / 32, 1, HH), dim3(256), 0, stream,
                       x, W_in, a_in, hb16, f1, f2);
    hipLaunchKernelGGL(gmax_kernel, dim3(HH), dim3(256), 0, stream, f2, gm);
    hipLaunchKernelGGL(transpose_kernel, dim3(NN / 32, FF / 32, HH), dim3(256), 0, stream, hb16, hT, FF);
    hipLaunchKernelGGL((agg2_kernel<FF, 1>), dim3(NN / 64, 1, HH), dim3(256), 0, stream,
                       hT, f1, f2, gm, mb, x, cat1, HH * FF);

    // ---- layer 2: Fin=512, D=64, 4 heads, elu, concat -> cat2[N,256]
    hipLaunchKernelGGL((proj_kernel<HH * FF, HIDD>), dim3(NN / 32, 1, HH), dim3(256), 0, stream,
                       cat1, W_hid, a_hid, hb16, f1, f2);
    hipLaunchKernelGGL(gmax_kernel, dim3(HH), dim3(256), 0, stream, f2, gm);
    hipLaunchKernelGGL(transpose_kernel, dim3(NN / 32, HIDD / 32, HH), dim3(256), 0, stream, hb16, hT, HIDD);
    hipLaunchKernelGGL((agg2_kernel<HIDD, 2>), dim3(NN / 64, 1, HH), dim3(256), 0, stream,
                       hT, f1, f2, gm, mb, (const float*)nullptr, cat2, HH * HIDD);

    // ---- layer 3: Fin=256, D=16, 1 head, no elu inside -> h3[N,16]
    hipLaunchKernelGGL((proj_kernel<HH * HIDD, OUTD>), dim3(NN / 32, 1, 1), dim3(256), 0, stream,
                       cat2, W_out, a_out, hb16, f1, f2);
    hipLaunchKernelGGL(gmax_kernel, dim3(1), dim3(256), 0, stream, f2, gm);
    hipLaunchKernelGGL(transpose_kernel, dim3(NN / 32, 1, 1), dim3(256), 0, stream, hb16, hT, OUTD);
    hipLaunchKernelGGL((agg_mfma_kernel<OUTD, 0, 4>), dim3(NN / 16, 1, 1), dim3(256), 0, stream,
                       hT, f1, f2, gm, mb, (const float*)nullptr, h3, OUTD);

    hipLaunchKernelGGL(final_kernel, dim3(NN / 256), dim3(256), 0, stream, h3, out);
}

// Round 5
// 388.432 us; speedup vs baseline: 3.4082x; 1.1565x over previous
//
#include <hip/hip_runtime.h>
#include <math.h>

#define NN 4096
#define FF 128
#define HH 4
#define HIDD 64
#define OUTD 16
#define MASKW (NN / 32)
#define ALPHA 0.2f

typedef __attribute__((ext_vector_type(8))) short short8;
typedef __attribute__((ext_vector_type(4))) float f32x4;

__device__ __forceinline__ ushort f2bf(float f) {  // RNE f32->bf16 (f >= 0 here, no NaN)
    unsigned u = __float_as_uint(f);
    return (ushort)((u + 0x7fffu + ((u >> 16) & 1u)) >> 16);
}

// ---------------- pack adjacency into bitmask (2 MB) ----------------
__global__ void pack_mask_kernel(const int* __restrict__ adj, unsigned int* __restrict__ mb) {
    int t = blockIdx.x * 256 + threadIdx.x;
    int v = adj[t] > 0;
    unsigned long long bal = __ballot(v);
    if ((threadIdx.x & 63) == 0) {
        int w = t >> 5;
        mb[w] = (unsigned int)(bal & 0xffffffffULL);
        mb[w + 1] = (unsigned int)(bal >> 32);
    }
}

// ---------------- projection + fused f1/f2: h bf16 out, scores fp32 ----------------
template <int FIN, int D>
__global__ __launch_bounds__(256) void proj_kernel(const float* __restrict__ A,
                                                   const float* __restrict__ W,
                                                   const float* __restrict__ av,
                                                   ushort* __restrict__ Hb,
                                                   float* __restrict__ f1,
                                                   float* __restrict__ f2) {
    constexpr int TI = 32, TF = 32;
    __shared__ float As[TI][TF + 1];
    __shared__ float Ws[TF][D];
    const int hd = blockIdx.z;
    const int i0 = blockIdx.x * TI;
    const float* Wh = W + (size_t)hd * FIN * D;
    const int t = threadIdx.x;
    const int r = t >> 3;
    const int c8 = t & 7;
    constexpr int VD = D / 8;
    float acc[VD];
#pragma unroll
    for (int k = 0; k < VD; k++) acc[k] = 0.f;
    for (int f0 = 0; f0 < FIN; f0 += TF) {
        for (int idx = t; idx < TI * TF; idx += 256) {
            int rr = idx >> 5, cc = idx & 31;
            As[rr][cc] = A[(size_t)(i0 + rr) * FIN + f0 + cc];
        }
        for (int idx = t; idx < TF * D; idx += 256) {
            int rr = idx / D, cc = idx % D;
            Ws[rr][cc] = Wh[(size_t)(f0 + rr) * D + cc];
        }
        __syncthreads();
#pragma unroll
        for (int f = 0; f < TF; f++) {
            float a = As[r][f];
#pragma unroll
            for (int k = 0; k < VD; k++) acc[k] += a * Ws[f][c8 * VD + k];
        }
        __syncthreads();
    }
    {
        const float* ah = av + hd * 2 * D;
        float s1 = 0.f, s2 = 0.f;
#pragma unroll
        for (int k = 0; k < VD; k++) {
            float hv = acc[k];
            s1 += hv * ah[c8 * VD + k];
            s2 += hv * ah[D + c8 * VD + k];
        }
#pragma unroll
        for (int o = 1; o < 8; o <<= 1) {
            s1 += __shfl_xor(s1, o);
            s2 += __shfl_xor(s2, o);
        }
        if (c8 == 0) {
            f1[hd * NN + i0 + r] = s1;
            f2[hd * NN + i0 + r] = s2;
        }
    }
    ushort* op = Hb + ((size_t)hd * NN + i0 + r) * D + c8 * VD;
#pragma unroll
    for (int k = 0; k < VD; k += 2) {
        unsigned pk = (unsigned)f2bf(acc[k]) | ((unsigned)f2bf(acc[k + 1]) << 16);
        *(unsigned*)&op[k] = pk;
    }
}

// ---------------- per-head global max of f2 ----------------
__global__ void gmax_kernel(const float* __restrict__ f2, float* __restrict__ gmax) {
    int hd = blockIdx.x;
    const float* p = f2 + (size_t)hd * NN;
    float m = -1e30f;
    for (int i = threadIdx.x; i < NN; i += 256) m = fmaxf(m, p[i]);
    __shared__ float sm[4];
#pragma unroll
    for (int off = 32; off > 0; off >>= 1) m = fmaxf(m, __shfl_down(m, off));
    if ((threadIdx.x & 63) == 0) sm[threadIdx.x >> 6] = m;
    __syncthreads();
    if (threadIdx.x == 0) gmax[hd] = fmaxf(fmaxf(sm[0], sm[1]), fmaxf(sm[2], sm[3]));
}

// ---------------- transpose h: [hd][N][D] bf16 -> [hd][D][N] bf16 ----------------
__global__ __launch_bounds__(256) void transpose_kernel(const ushort* __restrict__ in,
                                                        ushort* __restrict__ out, int D) {
    __shared__ ushort ts[32][33];
    const int hd = blockIdx.z;
    in += (size_t)hd * NN * D;
    out += (size_t)hd * D * NN;
    const int j0 = blockIdx.x * 32, d0 = blockIdx.y * 32;
    const int tx = threadIdx.x & 31, ty = threadIdx.x >> 5;
#pragma unroll
    for (int k = 0; k < 4; k++) {
        int row = ty + 8 * k;
        if (d0 + tx < D) ts[row][tx] = in[(size_t)(j0 + row) * D + d0 + tx];
    }
    __syncthreads();
#pragma unroll
    for (int k = 0; k < 4; k++) {
        int dr = ty + 8 * k;
        if (d0 + dr < D) out[(size_t)(d0 + dr) * NN + j0 + tx] = ts[tx][dr];
    }
}

// ---------------- j-split staged MFMA aggregation (L1/L2): writes fp32 partials ----------------
// grid (N/64, JS, H); block 4 waves x 16 rows. Block handles j in [jb, jb+NN/JS).
// pacc[((js*H + hd)*N + row)*D + col], plsum[(js*H + hd)*N + row].
template <int D>
__global__ __launch_bounds__(256) void agg3_kernel(const ushort* __restrict__ hT,
                                                   const float* __restrict__ f1,
                                                   const float* __restrict__ f2,
                                                   const float* __restrict__ gmax,
                                                   const unsigned int* __restrict__ mb,
                                                   float* __restrict__ pacc,
                                                   float* __restrict__ plsum) {
    constexpr int NT = D / 16;
    constexpr int NC = D / 64;
    __shared__ ushort hs[D][40];
    const int hd = blockIdx.z;
    const int js = blockIdx.y;
    const int jlen = NN / gridDim.y;
    const int jb = js * jlen, je = jb + jlen;
    const int t = threadIdx.x;
    const int w = t >> 6;
    const int lane = t & 63;
    const int ln = lane & 15;
    const int g = lane >> 4;
    const int g8 = g * 8;
    const int i0 = blockIdx.x * 64 + w * 16;
    const ushort* hTh = hT + (size_t)hd * D * NN;

    const float f1v = f1[hd * NN + i0 + ln];
    const float gm = gmax[hd];
    float mi = f1v + gm;
    mi = fmaxf(mi, ALPHA * mi);
    const float L2E = 1.442695040888963f;
    const float cexp = -mi * L2E;

    f32x4 acc[NT];
#pragma unroll
    for (int n = 0; n < NT; n++) acc[n] = (f32x4)(0.f);
    float lsum = 0.f;
    const float* f2h = f2 + hd * NN;
    const unsigned* mrow = mb + (size_t)(i0 + ln) * MASKW;

    int srow[NC], scol[NC];
#pragma unroll
    for (int c = 0; c < NC; c++) {
        int ch = t + c * 256;
        srow[c] = ch >> 2;
        scol[c] = (ch & 3) * 8;
    }
    uint4 st[NC];
#pragma unroll
    for (int c = 0; c < NC; c++)
        st[c] = *(const uint4*)&hTh[(size_t)srow[c] * NN + jb + scol[c]];
    unsigned mw = mrow[jb >> 5];
    f32x4 fA = *(const f32x4*)&f2h[jb + g8];
    f32x4 fB = *(const f32x4*)&f2h[jb + g8 + 4];

    for (int j0 = jb; j0 < je; j0 += 32) {
        __syncthreads();
#pragma unroll
        for (int c = 0; c < NC; c++) *(uint4*)&hs[srow[c]][scol[c]] = st[c];
        __syncthreads();
        const bool more = (j0 + 32) < je;
        if (more) {
#pragma unroll
            for (int c = 0; c < NC; c++)
                st[c] = *(const uint4*)&hTh[(size_t)srow[c] * NN + j0 + 32 + scol[c]];
        }
        unsigned bits = (mw >> g8) & 0xffu;
        f32x4 cA = fA, cB = fB;
        if (more) {
            mw = mrow[(j0 + 32) >> 5];
            fA = *(const f32x4*)&f2h[j0 + 32 + g8];
            fB = *(const f32x4*)&f2h[j0 + 32 + g8 + 4];
        }
        unsigned au[4];
#pragma unroll
        for (int tp = 0; tp < 4; tp++) {
            unsigned pu[2];
#pragma unroll
            for (int q = 0; q < 2; q++) {
                int tt = tp * 2 + q;
                float f2t = (tt < 4) ? cA[tt] : cB[tt - 4];
                float e = f1v + f2t;
                e = fmaxf(e, ALPHA * e);
                float p = ((bits >> tt) & 1u) ? __builtin_amdgcn_exp2f(e * L2E + cexp) : 0.f;
                pu[q] = __float_as_uint(p) & 0xffff0000u;
                lsum += __uint_as_float(pu[q]);
            }
            au[tp] = (pu[0] >> 16) | pu[1];
        }
        union { unsigned u[4]; short8 s; } aF;
#pragma unroll
        for (int q = 0; q < 4; q++) aF.u[q] = au[q];
#pragma unroll
        for (int n = 0; n < NT; n++) {
            short8 bF = *(const short8*)&hs[n * 16 + ln][g8];
            acc[n] = __builtin_amdgcn_mfma_f32_16x16x32_bf16(aF.s, bF, acc[n], 0, 0, 0);
        }
    }
    lsum += __shfl_xor(lsum, 16);
    lsum += __shfl_xor(lsum, 32);
    const size_t pbase = ((size_t)js * HH + hd) * NN;
    if (g == 0) plsum[pbase + i0 + ln] = lsum;
    float* pb = pacc + pbase * D;
#pragma unroll
    for (int n = 0; n < NT; n++) {
#pragma unroll
        for (int r = 0; r < 4; r++) {
            pb[(size_t)(i0 + g * 4 + r) * D + n * 16 + ln] = acc[n][r];
        }
    }
}

// ---------------- combine partials: normalize + epilogue ----------------
template <int D, int EPI>
__global__ __launch_bounds__(256) void combine_kernel(const float* __restrict__ pacc,
                                                      const float* __restrict__ plsum,
                                                      const float* __restrict__ xres,
                                                      float* __restrict__ out,
                                                      int ncols, int JS) {
    const int hd = blockIdx.y;
    const int e = (blockIdx.x * 256 + threadIdx.x) * 4;
    const int row = e / D;
    const int col = e % D;
    f32x4 s = (f32x4)(0.f);
    float l = 0.f;
    for (int js = 0; js < JS; js++) {
        const size_t pbase = ((size_t)js * HH + hd) * NN;
        s += *(const f32x4*)&pacc[(pbase + row) * D + col];
        l += plsum[pbase + row];
    }
    const float inv = 1.f / l;
    f32x4 xv;
    if (EPI == 1) xv = *(const f32x4*)&xres[(size_t)row * D + col];
    float* op = &out[(size_t)row * ncols + hd * D + col];
    f32x4 o;
#pragma unroll
    for (int k = 0; k < 4; k++) {
        float v = s[k] * inv;
        if (EPI == 1) v += xv[k];
        if (EPI >= 1) v = v > 0.f ? v : (__expf(v) - 1.f);
        o[k] = v;
    }
    *(f32x4*)op = o;
}

// ---------------- r4 fallback: staged multi-wave MFMA aggregation (no j-split) ----------------
template <int D, int EPI>
__global__ __launch_bounds__(256) void agg2_kernel(const ushort* __restrict__ hT,
                                                   const float* __restrict__ f1,
                                                   const float* __restrict__ f2,
                                                   const float* __restrict__ gmax,
                                                   const unsigned int* __restrict__ mb,
                                                   const float* __restrict__ xres,
                                                   float* __restrict__ out, int ncols) {
    constexpr int NT = D / 16;
    constexpr int NC = D / 64;
    __shared__ ushort hs[D][40];
    const int hd = blockIdx.z;
    const int t = threadIdx.x;
    const int w = t >> 6;
    const int lane = t & 63;
    const int ln = lane & 15;
    const int g = lane >> 4;
    const int g8 = g * 8;
    const int i0 = blockIdx.x * 64 + w * 16;
    const ushort* hTh = hT + (size_t)hd * D * NN;
    const float f1v = f1[hd * NN + i0 + ln];
    const float gm = gmax[hd];
    float mi = f1v + gm;
    mi = fmaxf(mi, ALPHA * mi);
    const float L2E = 1.442695040888963f;
    const float cexp = -mi * L2E;
    f32x4 acc[NT];
#pragma unroll
    for (int n = 0; n < NT; n++) acc[n] = (f32x4)(0.f);
    float lsum = 0.f;
    const float* f2h = f2 + hd * NN;
    const unsigned* mrow = mb + (size_t)(i0 + ln) * MASKW;
    int srow[NC], scol[NC];
#pragma unroll
    for (int c = 0; c < NC; c++) {
        int ch = t + c * 256;
        srow[c] = ch >> 2;
        scol[c] = (ch & 3) * 8;
    }
    uint4 st[NC];
#pragma unroll
    for (int c = 0; c < NC; c++)
        st[c] = *(const uint4*)&hTh[(size_t)srow[c] * NN + scol[c]];
    unsigned mw = mrow[0];
    f32x4 fA = *(const f32x4*)&f2h[g8];
    f32x4 fB = *(const f32x4*)&f2h[g8 + 4];
    for (int j0 = 0; j0 < NN; j0 += 32) {
        __syncthreads();
#pragma unroll
        for (int c = 0; c < NC; c++) *(uint4*)&hs[srow[c]][scol[c]] = st[c];
        __syncthreads();
        const bool more = (j0 + 32) < NN;
        if (more) {
#pragma unroll
            for (int c = 0; c < NC; c++)
                st[c] = *(const uint4*)&hTh[(size_t)srow[c] * NN + j0 + 32 + scol[c]];
        }
        unsigned bits = (mw >> g8) & 0xffu;
        f32x4 cA = fA, cB = fB;
        if (more) {
            mw = mrow[(j0 + 32) >> 5];
            fA = *(const f32x4*)&f2h[j0 + 32 + g8];
            fB = *(const f32x4*)&f2h[j0 + 32 + g8 + 4];
        }
        unsigned au[4];
#pragma unroll
        for (int tp = 0; tp < 4; tp++) {
            unsigned pu[2];
#pragma unroll
            for (int q = 0; q < 2; q++) {
                int tt = tp * 2 + q;
                float f2t = (tt < 4) ? cA[tt] : cB[tt - 4];
                float e = f1v + f2t;
                e = fmaxf(e, ALPHA * e);
                float p = ((bits >> tt) & 1u) ? __builtin_amdgcn_exp2f(e * L2E + cexp) : 0.f;
                pu[q] = __float_as_uint(p) & 0xffff0000u;
                lsum += __uint_as_float(pu[q]);
            }
            au[tp] = (pu[0] >> 16) | pu[1];
        }
        union { unsigned u[4]; short8 s; } aF;
#pragma unroll
        for (int q = 0; q < 4; q++) aF.u[q] = au[q];
#pragma unroll
        for (int n = 0; n < NT; n++) {
            short8 bF = *(const short8*)&hs[n * 16 + ln][g8];
            acc[n] = __builtin_amdgcn_mfma_f32_16x16x32_bf16(aF.s, bF, acc[n], 0, 0, 0);
        }
    }
    lsum += __shfl_xor(lsum, 16);
    lsum += __shfl_xor(lsum, 32);
    const float linv = 1.f / lsum;
#pragma unroll
    for (int n = 0; n < NT; n++) {
#pragma unroll
        for (int r = 0; r < 4; r++) {
            float invr = __shfl(linv, (g << 2) + r);
            float v = acc[n][r] * invr;
            int row = i0 + g * 4 + r;
            int col = n * 16 + ln;
            if (EPI == 1) v += xres[(size_t)row * D + col];
            if (EPI >= 1) v = v > 0.f ? v : (__expf(v) - 1.f);
            out[(size_t)row * ncols + hd * D + col] = v;
        }
    }
}

// ---------------- single-wave MFMA aggregation with in-block j-split (L3, D=16) ----------------
template <int D, int EPI, int NW>
__global__ __launch_bounds__(NW * 64) void agg_mfma_kernel(const ushort* __restrict__ hT,
                                                           const float* __restrict__ f1,
                                                           const float* __restrict__ f2,
                                                           const float* __restrict__ gmax,
                                                           const unsigned int* __restrict__ mb,
                                                           const float* __restrict__ xres,
                                                           float* __restrict__ out, int ncols) {
    constexpr int NT = D / 16;
    static_assert(NW == 1 || NT == 1, "j-split only for single-tile D");
    const int hd = blockIdx.z;
    const int i0 = blockIdx.x * 16;
    const int w = threadIdx.x >> 6;
    const int lane = threadIdx.x & 63;
    const int ln = lane & 15;
    const int g = lane >> 4;
    const int g8 = g * 8;
    const ushort* hTh = hT + (size_t)hd * D * NN;
    const float f1v = f1[hd * NN + i0 + ln];
    const float gm = gmax[hd];
    float mi = f1v + gm;
    mi = fmaxf(mi, ALPHA * mi);
    f32x4 acc[NT];
#pragma unroll
    for (int n = 0; n < NT; n++) acc[n] = (f32x4)(0.f);
    float lsum = 0.f;
    const float* f2h = f2 + hd * NN;
    const unsigned* mrow = mb + (size_t)(i0 + ln) * MASKW;
    const int jbeg = w * (NN / NW), jend = jbeg + NN / NW;

    for (int j0 = jbeg; j0 < jend; j0 += 32) {
        unsigned bits = (mrow[j0 >> 5] >> g8) & 0xffu;
        f32x4 fA = *(const f32x4*)&f2h[j0 + g8];
        f32x4 fB = *(const f32x4*)&f2h[j0 + g8 + 4];
        short8 aF;
#pragma unroll
        for (int t = 0; t < 8; t++) {
            float f2t = (t < 4) ? fA[t] : fB[t - 4];
            float e = f1v + f2t;
            e = fmaxf(e, ALPHA * e);
            float p = ((bits >> t) & 1u) ? __expf(e - mi) : 0.f;
            ushort pb = f2bf(p);
            aF[t] = (short)pb;
            lsum += __uint_as_float((unsigned)pb << 16);
        }
#pragma unroll
        for (int n = 0; n < NT; n++) {
            short8 bF = *(const short8*)&hTh[(size_t)(n * 16 + ln) * NN + j0 + g8];
            acc[n] = __builtin_amdgcn_mfma_f32_16x16x32_bf16(aF, bF, acc[n], 0, 0, 0);
        }
    }
    lsum += __shfl_xor(lsum, 16);
    lsum += __shfl_xor(lsum, 32);

    float accF[NT][4];
    float ltot;
    __shared__ float accL[NW][16][17];
    __shared__ float lsL[NW][16];
    if constexpr (NW == 1) {
#pragma unroll
        for (int n = 0; n < NT; n++)
#pragma unroll
            for (int r = 0; r < 4; r++) accF[n][r] = acc[n][r];
        ltot = lsum;
    } else {
#pragma unroll
        for (int r = 0; r < 4; r++) accL[w][g * 4 + r][ln] = acc[0][r];
        if (lane < 16) lsL[w][lane] = lsum;
        __syncthreads();
        if (w != 0) return;
#pragma unroll
        for (int r = 0; r < 4; r++) {
            float s = 0.f;
            for (int ww = 0; ww < NW; ww++) s += accL[ww][g * 4 + r][ln];
            accF[0][r] = s;
        }
        float s = 0.f;
        for (int ww = 0; ww < NW; ww++) s += lsL[ww][ln];
        ltot = s;
    }
    const float linv = 1.f / ltot;
#pragma unroll
    for (int n = 0; n < NT; n++) {
#pragma unroll
        for (int r = 0; r < 4; r++) {
            float invr = __shfl(linv, (g << 2) + r);
            float v = accF[n][r] * invr;
            int row = i0 + g * 4 + r;
            int col = n * 16 + ln;
            if (EPI == 1) v += xres[(size_t)row * D + col];
            if (EPI >= 1) v = v > 0.f ? v : (__expf(v) - 1.f);
            out[(size_t)row * ncols + hd * D + col] = v;
        }
    }
}

// ---------------- final: log_softmax(elu(h3)) over 16 cols ----------------
__global__ void final_kernel(const float* __restrict__ h3, float* __restrict__ out) {
    int i = blockIdx.x * 256 + threadIdx.x;
    if (i >= NN) return;
    float v[OUTD];
    float mx = -1e30f;
#pragma unroll
    for (int k = 0; k < OUTD; k++) {
        float e = h3[(size_t)i * OUTD + k];
        e = e > 0.f ? e : (__expf(e) - 1.f);
        v[k] = e;
        mx = fmaxf(mx, e);
    }
    float s = 0.f;
#pragma unroll
    for (int k = 0; k < OUTD; k++) s += __expf(v[k] - mx);
    float ls = logf(s);
#pragma unroll
    for (int k = 0; k < OUTD; k++) out[(size_t)i * OUTD + k] = v[k] - mx - ls;
}

extern "C" void kernel_launch(void* const* d_in, const int* in_sizes, int n_in,
                              void* d_out, int out_size, void* d_ws, size_t ws_size,
                              hipStream_t stream) {
    const float* x = (const float*)d_in[0];
    const int* adj = (const int*)d_in[1];
    const float* W_in = (const float*)d_in[2];
    const float* a_in = (const float*)d_in[3];
    const float* W_hid = (const float*)d_in[4];
    const float* a_hid = (const float*)d_in[5];
    const float* W_out = (const float*)d_in[6];
    const float* a_out = (const float*)d_in[7];
    float* out = (float*)d_out;

    char* w = (char*)d_ws;
    unsigned int* mb = (unsigned int*)w;  w += (size_t)NN * MASKW * 4;            // 2 MB
    ushort* hb16 = (ushort*)w;            w += (size_t)HH * NN * FF * 2;          // 4 MB
    ushort* hT = (ushort*)w;              w += (size_t)HH * NN * FF * 2;          // 4 MB
    float* cat1 = (float*)w;              w += (size_t)NN * (HH * FF) * 4;        // 8 MB
    float* f1 = (float*)w;                w += (size_t)HH * NN * 4;
    float* f2 = (float*)w;                w += (size_t)HH * NN * 4;
    float* gm = (float*)w;                w += 256;
    float* h3 = (float*)w;                w += (size_t)NN * OUTD * 4;             // 256 KB
    float* cat2 = cat1;                                                           // alias
    size_t base_used = (size_t)(w - (char*)d_ws);

    // j-split factor chosen from available workspace (constant across calls)
    int JS = 0;  // 0 -> fallback (no partials)
    float* pacc = (float*)w;
    float* plsum = nullptr;
    {
        size_t per_js = (size_t)HH * NN * FF * 4;       // pacc bytes per L1 js
        size_t ls_per_js = (size_t)HH * NN * 4;         // plsum bytes per js (x2 for L2's 2*JS)
        for (int cand = 4; cand >= 1; cand >>= 1) {
            size_t need = base_used + (size_t)cand * per_js + (size_t)(2 * cand) * ls_per_js + 1024;
            if (ws_size >= need) { JS = cand; break; }
        }
        if (JS) plsum = (float*)((char*)pacc + (size_t)JS * per_js);
    }
    const int JS2 = 2 * JS;  // layer-2 j-split (same pacc footprint since D halves)

    hipLaunchKernelGGL(pack_mask_kernel, dim3(NN * NN / 256), dim3(256), 0, stream, adj, mb);

    // ---- layer 1: Fin=128, D=128, 4 heads, residual+elu, concat -> cat1[N,512]
    hipLaunchKernelGGL((proj_kernel<FF, FF>), dim3(NN / 32, 1, HH), dim3(256), 0, stream,
                       x, W_in, a_in, hb16, f1, f2);
    hipLaunchKernelGGL(gmax_kernel, dim3(HH), dim3(256), 0, stream, f2, gm);
    hipLaunchKernelGGL(transpose_kernel, dim3(NN / 32, FF / 32, HH), dim3(256), 0, stream, hb16, hT, FF);
    if (JS) {
        hipLaunchKernelGGL((agg3_kernel<FF>), dim3(NN / 64, JS, HH), dim3(256), 0, stream,
                           hT, f1, f2, gm, mb, pacc, plsum);
        hipLaunchKernelGGL((combine_kernel<FF, 1>), dim3(NN * FF / 1024, HH), dim3(256), 0, stream,
                           pacc, plsum, x, cat1, HH * FF, JS);
    } else {
        hipLaunchKernelGGL((agg2_kernel<FF, 1>), dim3(NN / 64, 1, HH), dim3(256), 0, stream,
                           hT, f1, f2, gm, mb, x, cat1, HH * FF);
    }

    // ---- layer 2: Fin=512, D=64, 4 heads, elu, concat -> cat2[N,256]
    hipLaunchKernelGGL((proj_kernel<HH * FF, HIDD>), dim3(NN / 32, 1, HH), dim3(256), 0, stream,
                       cat1, W_hid, a_hid, hb16, f1, f2);
    hipLaunchKernelGGL(gmax_kernel, dim3(HH), dim3(256), 0, stream, f2, gm);
    hipLaunchKernelGGL(transpose_kernel, dim3(NN / 32, HIDD / 32, HH), dim3(256), 0, stream, hb16, hT, HIDD);
    if (JS) {
        hipLaunchKernelGGL((agg3_kernel<HIDD>), dim3(NN / 64, JS2, HH), dim3(256), 0, stream,
                           hT, f1, f2, gm, mb, pacc, plsum);
        hipLaunchKernelGGL((combine_kernel<HIDD, 2>), dim3(NN * HIDD / 1024, HH), dim3(256), 0, stream,
                           pacc, plsum, (const float*)nullptr, cat2, HH * HIDD, JS2);
    } else {
        hipLaunchKernelGGL((agg2_kernel<HIDD, 2>), dim3(NN / 64, 1, HH), dim3(256), 0, stream,
                           hT, f1, f2, gm, mb, (const float*)nullptr, cat2, HH * HIDD);
    }

    // ---- layer 3: Fin=256, D=16, 1 head, no elu inside -> h3[N,16]
    hipLaunchKernelGGL((proj_kernel<HH * HIDD, OUTD>), dim3(NN / 32, 1, 1), dim3(256), 0, stream,
                       cat2, W_out, a_out, hb16, f1, f2);
    hipLaunchKernelGGL(gmax_kernel, dim3(1), dim3(256), 0, stream, f2, gm);
    hipLaunchKernelGGL(transpose_kernel, dim3(NN / 32, 1, 1), dim3(256), 0, stream, hb16, hT, OUTD);
    hipLaunchKernelGGL((agg_mfma_kernel<OUTD, 0, 4>), dim3(NN / 16, 1, 1), dim3(256), 0, stream,
                       hT, f1, f2, gm, mb, (const float*)nullptr, h3, OUTD);

    hipLaunchKernelGGL(final_kernel, dim3(NN / 256), dim3(256), 0, stream, h3, out);
}

// Round 6
// 339.336 us; speedup vs baseline: 3.9013x; 1.1447x over previous
//
#include <hip/hip_runtime.h>
#include <math.h>

#define NN 4096
#define FF 128
#define HH 4
#define HIDD 64
#define OUTD 16
#define MASKW (NN / 32)
#define ALPHA 0.2f

typedef __attribute__((ext_vector_type(8))) short short8;
typedef __attribute__((ext_vector_type(4))) float f32x4;

__device__ __forceinline__ ushort f2bf(float f) {  // RNE f32->bf16 (finite, no NaN)
    unsigned u = __float_as_uint(f);
    return (ushort)((u + 0x7fffu + ((u >> 16) & 1u)) >> 16);
}
__device__ __forceinline__ float bf2f(ushort u) {
    return __uint_as_float((unsigned)u << 16);
}

// ---------------- pack adjacency into bitmask (2 MB) ----------------
__global__ void pack_mask_kernel(const int* __restrict__ adj, unsigned int* __restrict__ mb) {
    int t = blockIdx.x * 256 + threadIdx.x;
    int v = adj[t] > 0;
    unsigned long long bal = __ballot(v);
    if ((threadIdx.x & 63) == 0) {
        int w = t >> 5;
        mb[w] = (unsigned int)(bal & 0xffffffffULL);
        mb[w + 1] = (unsigned int)(bal >> 32);
    }
}

// ---------------- cvt x -> bf16 ----------------
__global__ void cvt_kernel(const float* __restrict__ x, ushort* __restrict__ xb) {
    int e = (blockIdx.x * 256 + threadIdx.x) * 4;
    f32x4 v = *(const f32x4*)&x[e];
    unsigned lo = (unsigned)f2bf(v[0]) | ((unsigned)f2bf(v[1]) << 16);
    unsigned hi = (unsigned)f2bf(v[2]) | ((unsigned)f2bf(v[3]) << 16);
    uint2 p; p.x = lo; p.y = hi;
    *(uint2*)&xb[e] = p;
}

// ---------------- weight transpose+cast: W[hd][k][n] fp32 -> WT[hd][n][k] bf16 ----------------
__global__ void wtprep_kernel(const float* __restrict__ W_in, const float* __restrict__ W_hid,
                              const float* __restrict__ W_out,
                              ushort* __restrict__ wt1, ushort* __restrict__ wt2,
                              ushort* __restrict__ wt3) {
    int idx = blockIdx.x * 256 + threadIdx.x;
    if (idx < 65536) {  // L1: H=4, K=128, N=128
        int k = idx & 127, n = (idx >> 7) & 127, hd = idx >> 14;
        wt1[idx] = f2bf(W_in[((size_t)hd * 128 + k) * 128 + n]);
    } else if (idx < 65536 + 131072) {  // L2: H=4, K=512, N=64
        int j = idx - 65536;
        int k = j & 511, n = (j >> 9) & 63, hd = j >> 15;
        wt2[j] = f2bf(W_hid[((size_t)hd * 512 + k) * 64 + n]);
    } else if (idx < 65536 + 131072 + 4096) {  // L3: K=256, N=16
        int j = idx - 196608;
        int k = j & 255, n = j >> 8;
        wt3[j] = f2bf(W_out[(size_t)k * 16 + n]);
    }
}

// ---------------- v = W . a per head (fp32): v[(s*H+hd)*K + f] ----------------
__global__ void vprep_kernel(const float* __restrict__ W_in, const float* __restrict__ a_in,
                             const float* __restrict__ W_hid, const float* __restrict__ a_hid,
                             const float* __restrict__ W_out, const float* __restrict__ a_out,
                             float* __restrict__ vbuf) {
    int idx = blockIdx.x * 256 + threadIdx.x;
    const float* Wr; const float* ar; int D; float* dst;
    if (idx < 1024) {  // L1: s,hd,f : K=128,D=128
        int f = idx & 127, hd = (idx >> 7) & 3, s = idx >> 9;
        Wr = W_in + ((size_t)hd * 128 + f) * 128;
        ar = a_in + hd * 256 + s * 128;
        D = 128; dst = &vbuf[idx];
    } else if (idx < 1024 + 4096) {  // L2: K=512,D=64
        int j = idx - 1024;
        int f = j & 511, hd = (j >> 9) & 3, s = j >> 11;
        Wr = W_hid + ((size_t)hd * 512 + f) * 64;
        ar = a_hid + hd * 128 + s * 64;
        D = 64; dst = &vbuf[1024 + j];
    } else if (idx < 1024 + 4096 + 512) {  // L3: K=256,D=16
        int j = idx - 5120;
        int f = j & 255, s = j >> 8;
        Wr = W_out + (size_t)f * 16;
        ar = a_out + s * 16;
        D = 16; dst = &vbuf[5120 + j];
    } else return;
    float s = 0.f;
    for (int d = 0; d < D; d++) s += Wr[d] * ar[d];
    *dst = s;
}

// ---------------- scores: f1/f2[hd][i] = A[i,:] . v{1,2}[hd,:]  (wave per (hd,i)) ----------------
template <typename T, int K, int H>
__global__ __launch_bounds__(256) void score_kernel(const T* __restrict__ A,
                                                    const float* __restrict__ v,
                                                    float* __restrict__ f1,
                                                    float* __restrict__ f2) {
    int wv = blockIdx.x * 4 + (threadIdx.x >> 6);  // wv = hd*NN + i
    int lane = threadIdx.x & 63;
    int hd = wv >> 12;
    int i = wv & (NN - 1);
    const T* ar = A + (size_t)i * K;
    const float* v1r = v + (size_t)hd * K;
    const float* v2r = v + (size_t)(H + hd) * K;
    float s1 = 0.f, s2 = 0.f;
    for (int f = lane; f < K; f += 64) {
        float av;
        if constexpr (sizeof(T) == 2) av = bf2f(((const ushort*)ar)[f]);
        else av = ((const float*)ar)[f];
        s1 += av * v1r[f];
        s2 += av * v2r[f];
    }
#pragma unroll
    for (int o = 32; o > 0; o >>= 1) {
        s1 += __shfl_down(s1, o);
        s2 += __shfl_down(s2, o);
    }
    if (lane == 0) { f1[wv] = s1; f2[wv] = s2; }
}

// ---------------- per-head global max of f2 ----------------
__global__ void gmax_kernel(const float* __restrict__ f2, float* __restrict__ gmax) {
    int hd = blockIdx.x;
    const float* p = f2 + (size_t)hd * NN;
    float m = -1e30f;
    for (int i = threadIdx.x; i < NN; i += 256) m = fmaxf(m, p[i]);
    __shared__ float sm[4];
#pragma unroll
    for (int off = 32; off > 0; off >>= 1) m = fmaxf(m, __shfl_down(m, off));
    if ((threadIdx.x & 63) == 0) sm[threadIdx.x >> 6] = m;
    __syncthreads();
    if (threadIdx.x == 0) gmax[hd] = fmaxf(fmaxf(sm[0], sm[1]), fmaxf(sm[2], sm[3]));
}

// ---------------- MFMA projection: hT[hd][n][i] = sum_k A[i][k] * WT[hd][n][k] ----------------
// CFG0: 4 waves share 16 rows, split N 4 ways (NT = N/64 tiles/wave).
// CFG1: 4 waves split 64 rows, full N each (NT = N/16). Epilogue transposes each
// 16x16 C-tile through a per-wave LDS tile into hT (no cross-wave sync needed).
template <int K, int N, int CFG>
__global__ __launch_bounds__(256) void proj_mfma_kernel(const ushort* __restrict__ A,
                                                        const ushort* __restrict__ WT,
                                                        ushort* __restrict__ hT) {
    constexpr int NT = (CFG == 0) ? (N / 64) : (N / 16);
    __shared__ ushort ts[4][NT * 16][20];
    const int hd = blockIdx.y;
    const int t = threadIdx.x;
    const int w = t >> 6, lane = t & 63, ln = lane & 15, g = lane >> 4, g8 = g * 8;
    const int i0 = (CFG == 0) ? blockIdx.x * 16 : blockIdx.x * 64 + w * 16;
    const int n0 = (CFG == 0) ? w * (N / 4) : 0;
    const ushort* WTh = WT + (size_t)hd * N * K;
    ushort* hTh = hT + (size_t)hd * N * NN;
    f32x4 acc[NT];
#pragma unroll
    for (int n = 0; n < NT; n++) acc[n] = (f32x4)(0.f);
    const ushort* arow = A + (size_t)(i0 + ln) * K + g8;
#pragma unroll
    for (int k0 = 0; k0 < K; k0 += 32) {
        short8 aF = *(const short8*)&arow[k0];
#pragma unroll
        for (int n = 0; n < NT; n++) {
            short8 bF = *(const short8*)&WTh[(size_t)(n0 + n * 16 + ln) * K + k0 + g8];
            acc[n] = __builtin_amdgcn_mfma_f32_16x16x32_bf16(aF, bF, acc[n], 0, 0, 0);
        }
    }
    // epilogue: C row=g*4+r, col=ln  ->  ts[w][d=col][i=row] -> hT[n][i] coalesced-ish
#pragma unroll
    for (int n = 0; n < NT; n++) {
        unsigned lo = (unsigned)f2bf(acc[n][0]) | ((unsigned)f2bf(acc[n][1]) << 16);
        unsigned hi = (unsigned)f2bf(acc[n][2]) | ((unsigned)f2bf(acc[n][3]) << 16);
        uint2 p; p.x = lo; p.y = hi;
        *(uint2*)&ts[w][n * 16 + ln][g * 4] = p;
    }
#pragma unroll
    for (int n = 0; n < NT; n++) {
        int d = lane >> 2, ip = lane & 3;
        uint2 rv = *(uint2*)&ts[w][n * 16 + d][ip * 4];
        *(uint2*)&hTh[(size_t)(n0 + n * 16 + d) * NN + i0 + ip * 4] = rv;
    }
}

// ---------------- j-split staged MFMA aggregation (L1/L2): writes fp32 partials ----------------
template <int D>
__global__ __launch_bounds__(256) void agg3_kernel(const ushort* __restrict__ hT,
                                                   const float* __restrict__ f1,
                                                   const float* __restrict__ f2,
                                                   const float* __restrict__ gmax,
                                                   const unsigned int* __restrict__ mb,
                                                   float* __restrict__ pacc,
                                                   float* __restrict__ plsum) {
    constexpr int NT = D / 16;
    constexpr int NC = D / 64;
    __shared__ ushort hs[D][40];
    const int hd = blockIdx.z;
    const int js = blockIdx.y;
    const int jlen = NN / gridDim.y;
    const int jb = js * jlen, je = jb + jlen;
    const int t = threadIdx.x;
    const int w = t >> 6;
    const int lane = t & 63;
    const int ln = lane & 15;
    const int g = lane >> 4;
    const int g8 = g * 8;
    const int i0 = blockIdx.x * 64 + w * 16;
    const ushort* hTh = hT + (size_t)hd * D * NN;

    const float f1v = f1[hd * NN + i0 + ln];
    const float gm = gmax[hd];
    float mi = f1v + gm;
    mi = fmaxf(mi, ALPHA * mi);
    const float L2E = 1.442695040888963f;
    const float cexp = -mi * L2E;

    f32x4 acc[NT];
#pragma unroll
    for (int n = 0; n < NT; n++) acc[n] = (f32x4)(0.f);
    float lsum = 0.f;
    const float* f2h = f2 + hd * NN;
    const unsigned* mrow = mb + (size_t)(i0 + ln) * MASKW;

    int srow[NC], scol[NC];
#pragma unroll
    for (int c = 0; c < NC; c++) {
        int ch = t + c * 256;
        srow[c] = ch >> 2;
        scol[c] = (ch & 3) * 8;
    }
    uint4 st[NC];
#pragma unroll
    for (int c = 0; c < NC; c++)
        st[c] = *(const uint4*)&hTh[(size_t)srow[c] * NN + jb + scol[c]];
    unsigned mw = mrow[jb >> 5];
    f32x4 fA = *(const f32x4*)&f2h[jb + g8];
    f32x4 fB = *(const f32x4*)&f2h[jb + g8 + 4];

    for (int j0 = jb; j0 < je; j0 += 32) {
        __syncthreads();
#pragma unroll
        for (int c = 0; c < NC; c++) *(uint4*)&hs[srow[c]][scol[c]] = st[c];
        __syncthreads();
        const bool more = (j0 + 32) < je;
        if (more) {
#pragma unroll
            for (int c = 0; c < NC; c++)
                st[c] = *(const uint4*)&hTh[(size_t)srow[c] * NN + j0 + 32 + scol[c]];
        }
        unsigned bits = (mw >> g8) & 0xffu;
        f32x4 cA = fA, cB = fB;
        if (more) {
            mw = mrow[(j0 + 32) >> 5];
            fA = *(const f32x4*)&f2h[j0 + 32 + g8];
            fB = *(const f32x4*)&f2h[j0 + 32 + g8 + 4];
        }
        unsigned au[4];
#pragma unroll
        for (int tp = 0; tp < 4; tp++) {
            unsigned pu[2];
#pragma unroll
            for (int q = 0; q < 2; q++) {
                int tt = tp * 2 + q;
                float f2t = (tt < 4) ? cA[tt] : cB[tt - 4];
                float e = f1v + f2t;
                e = fmaxf(e, ALPHA * e);
                float p = ((bits >> tt) & 1u) ? __builtin_amdgcn_exp2f(e * L2E + cexp) : 0.f;
                pu[q] = __float_as_uint(p) & 0xffff0000u;
                lsum += __uint_as_float(pu[q]);
            }
            au[tp] = (pu[0] >> 16) | pu[1];
        }
        union { unsigned u[4]; short8 s; } aF;
#pragma unroll
        for (int q = 0; q < 4; q++) aF.u[q] = au[q];
#pragma unroll
        for (int n = 0; n < NT; n++) {
            short8 bF = *(const short8*)&hs[n * 16 + ln][g8];
            acc[n] = __builtin_amdgcn_mfma_f32_16x16x32_bf16(aF.s, bF, acc[n], 0, 0, 0);
        }
    }
    lsum += __shfl_xor(lsum, 16);
    lsum += __shfl_xor(lsum, 32);
    const size_t pbase = ((size_t)js * HH + hd) * NN;
    if (g == 0) plsum[pbase + i0 + ln] = lsum;
    float* pb = pacc + pbase * D;
#pragma unroll
    for (int n = 0; n < NT; n++) {
#pragma unroll
        for (int r = 0; r < 4; r++) {
            pb[(size_t)(i0 + g * 4 + r) * D + n * 16 + ln] = acc[n][r];
        }
    }
}

// ---------------- combine partials: normalize + epilogue -> bf16 concat ----------------
template <int D, int EPI>
__global__ __launch_bounds__(256) void combine_kernel(const float* __restrict__ pacc,
                                                      const float* __restrict__ plsum,
                                                      const float* __restrict__ xres,
                                                      ushort* __restrict__ out,
                                                      int ncols, int JS) {
    const int hd = blockIdx.y;
    const int e = (blockIdx.x * 256 + threadIdx.x) * 4;
    const int row = e / D;
    const int col = e % D;
    f32x4 s = (f32x4)(0.f);
    float l = 0.f;
    for (int js = 0; js < JS; js++) {
        const size_t pbase = ((size_t)js * HH + hd) * NN;
        s += *(const f32x4*)&pacc[(pbase + row) * D + col];
        l += plsum[pbase + row];
    }
    const float inv = 1.f / l;
    f32x4 xv;
    if (EPI == 1) xv = *(const f32x4*)&xres[(size_t)row * D + col];
    float o[4];
#pragma unroll
    for (int k = 0; k < 4; k++) {
        float v = s[k] * inv;
        if (EPI == 1) v += xv[k];
        if (EPI >= 1) v = v > 0.f ? v : (__expf(v) - 1.f);
        o[k] = v;
    }
    unsigned lo = (unsigned)f2bf(o[0]) | ((unsigned)f2bf(o[1]) << 16);
    unsigned hi = (unsigned)f2bf(o[2]) | ((unsigned)f2bf(o[3]) << 16);
    uint2 p; p.x = lo; p.y = hi;
    *(uint2*)&out[(size_t)row * ncols + hd * D + col] = p;
}

// ---------------- fallback: staged multi-wave MFMA aggregation (no j-split) ----------------
template <int D, int EPI>
__global__ __launch_bounds__(256) void agg2_kernel(const ushort* __restrict__ hT,
                                                   const float* __restrict__ f1,
                                                   const float* __restrict__ f2,
                                                   const float* __restrict__ gmax,
                                                   const unsigned int* __restrict__ mb,
                                                   const float* __restrict__ xres,
                                                   ushort* __restrict__ out, int ncols) {
    constexpr int NT = D / 16;
    constexpr int NC = D / 64;
    __shared__ ushort hs[D][40];
    const int hd = blockIdx.z;
    const int t = threadIdx.x;
    const int w = t >> 6;
    const int lane = t & 63;
    const int ln = lane & 15;
    const int g = lane >> 4;
    const int g8 = g * 8;
    const int i0 = blockIdx.x * 64 + w * 16;
    const ushort* hTh = hT + (size_t)hd * D * NN;
    const float f1v = f1[hd * NN + i0 + ln];
    const float gm = gmax[hd];
    float mi = f1v + gm;
    mi = fmaxf(mi, ALPHA * mi);
    const float L2E = 1.442695040888963f;
    const float cexp = -mi * L2E;
    f32x4 acc[NT];
#pragma unroll
    for (int n = 0; n < NT; n++) acc[n] = (f32x4)(0.f);
    float lsum = 0.f;
    const float* f2h = f2 + hd * NN;
    const unsigned* mrow = mb + (size_t)(i0 + ln) * MASKW;
    int srow[NC], scol[NC];
#pragma unroll
    for (int c = 0; c < NC; c++) {
        int ch = t + c * 256;
        srow[c] = ch >> 2;
        scol[c] = (ch & 3) * 8;
    }
    uint4 st[NC];
#pragma unroll
    for (int c = 0; c < NC; c++)
        st[c] = *(const uint4*)&hTh[(size_t)srow[c] * NN + scol[c]];
    unsigned mw = mrow[0];
    f32x4 fA = *(const f32x4*)&f2h[g8];
    f32x4 fB = *(const f32x4*)&f2h[g8 + 4];
    for (int j0 = 0; j0 < NN; j0 += 32) {
        __syncthreads();
#pragma unroll
        for (int c = 0; c < NC; c++) *(uint4*)&hs[srow[c]][scol[c]] = st[c];
        __syncthreads();
        const bool more = (j0 + 32) < NN;
        if (more) {
#pragma unroll
            for (int c = 0; c < NC; c++)
                st[c] = *(const uint4*)&hTh[(size_t)srow[c] * NN + j0 + 32 + scol[c]];
        }
        unsigned bits = (mw >> g8) & 0xffu;
        f32x4 cA = fA, cB = fB;
        if (more) {
            mw = mrow[(j0 + 32) >> 5];
            fA = *(const f32x4*)&f2h[j0 + 32 + g8];
            fB = *(const f32x4*)&f2h[j0 + 32 + g8 + 4];
        }
        unsigned au[4];
#pragma unroll
        for (int tp = 0; tp < 4; tp++) {
            unsigned pu[2];
#pragma unroll
            for (int q = 0; q < 2; q++) {
                int tt = tp * 2 + q;
                float f2t = (tt < 4) ? cA[tt] : cB[tt - 4];
                float e = f1v + f2t;
                e = fmaxf(e, ALPHA * e);
                float p = ((bits >> tt) & 1u) ? __builtin_amdgcn_exp2f(e * L2E + cexp) : 0.f;
                pu[q] = __float_as_uint(p) & 0xffff0000u;
                lsum += __uint_as_float(pu[q]);
            }
            au[tp] = (pu[0] >> 16) | pu[1];
        }
        union { unsigned u[4]; short8 s; } aF;
#pragma unroll
        for (int q = 0; q < 4; q++) aF.u[q] = au[q];
#pragma unroll
        for (int n = 0; n < NT; n++) {
            short8 bF = *(const short8*)&hs[n * 16 + ln][g8];
            acc[n] = __builtin_amdgcn_mfma_f32_16x16x32_bf16(aF.s, bF, acc[n], 0, 0, 0);
        }
    }
    lsum += __shfl_xor(lsum, 16);
    lsum += __shfl_xor(lsum, 32);
    const float linv = 1.f / lsum;
#pragma unroll
    for (int n = 0; n < NT; n++) {
#pragma unroll
        for (int r = 0; r < 4; r++) {
            float invr = __shfl(linv, (g << 2) + r);
            float v = acc[n][r] * invr;
            int row = i0 + g * 4 + r;
            int col = n * 16 + ln;
            if (EPI == 1) v += xres[(size_t)row * D + col];
            if (EPI >= 1) v = v > 0.f ? v : (__expf(v) - 1.f);
            out[(size_t)row * ncols + hd * D + col] = f2bf(v);
        }
    }
}

// ---------------- single-wave MFMA aggregation with in-block j-split (L3, D=16) ----------------
template <int D, int EPI, int NW>
__global__ __launch_bounds__(NW * 64) void agg_mfma_kernel(const ushort* __restrict__ hT,
                                                           const float* __restrict__ f1,
                                                           const float* __restrict__ f2,
                                                           const float* __restrict__ gmax,
                                                           const unsigned int* __restrict__ mb,
                                                           const float* __restrict__ xres,
                                                           float* __restrict__ out, int ncols) {
    constexpr int NT = D / 16;
    static_assert(NW == 1 || NT == 1, "j-split only for single-tile D");
    const int hd = blockIdx.z;
    const int i0 = blockIdx.x * 16;
    const int w = threadIdx.x >> 6;
    const int lane = threadIdx.x & 63;
    const int ln = lane & 15;
    const int g = lane >> 4;
    const int g8 = g * 8;
    const ushort* hTh = hT + (size_t)hd * D * NN;
    const float f1v = f1[hd * NN + i0 + ln];
    const float gm = gmax[hd];
    float mi = f1v + gm;
    mi = fmaxf(mi, ALPHA * mi);
    f32x4 acc[NT];
#pragma unroll
    for (int n = 0; n < NT; n++) acc[n] = (f32x4)(0.f);
    float lsum = 0.f;
    const float* f2h = f2 + hd * NN;
    const unsigned* mrow = mb + (size_t)(i0 + ln) * MASKW;
    const int jbeg = w * (NN / NW), jend = jbeg + NN / NW;

    for (int j0 = jbeg; j0 < jend; j0 += 32) {
        unsigned bits = (mrow[j0 >> 5] >> g8) & 0xffu;
        f32x4 fA = *(const f32x4*)&f2h[j0 + g8];
        f32x4 fB = *(const f32x4*)&f2h[j0 + g8 + 4];
        short8 aF;
#pragma unroll
        for (int t = 0; t < 8; t++) {
            float f2t = (t < 4) ? fA[t] : fB[t - 4];
            float e = f1v + f2t;
            e = fmaxf(e, ALPHA * e);
            float p = ((bits >> t) & 1u) ? __expf(e - mi) : 0.f;
            ushort pb = f2bf(p);
            aF[t] = (short)pb;
            lsum += __uint_as_float((unsigned)pb << 16);
        }
#pragma unroll
        for (int n = 0; n < NT; n++) {
            short8 bF = *(const short8*)&hTh[(size_t)(n * 16 + ln) * NN + j0 + g8];
            acc[n] = __builtin_amdgcn_mfma_f32_16x16x32_bf16(aF, bF, acc[n], 0, 0, 0);
        }
    }
    lsum += __shfl_xor(lsum, 16);
    lsum += __shfl_xor(lsum, 32);

    float accF[NT][4];
    float ltot;
    __shared__ float accL[NW][16][17];
    __shared__ float lsL[NW][16];
    if constexpr (NW == 1) {
#pragma unroll
        for (int n = 0; n < NT; n++)
#pragma unroll
            for (int r = 0; r < 4; r++) accF[n][r] = acc[n][r];
        ltot = lsum;
    } else {
#pragma unroll
        for (int r = 0; r < 4; r++) accL[w][g * 4 + r][ln] = acc[0][r];
        if (lane < 16) lsL[w][lane] = lsum;
        __syncthreads();
        if (w != 0) return;
#pragma unroll
        for (int r = 0; r < 4; r++) {
            float s = 0.f;
            for (int ww = 0; ww < NW; ww++) s += accL[ww][g * 4 + r][ln];
            accF[0][r] = s;
        }
        float s = 0.f;
        for (int ww = 0; ww < NW; ww++) s += lsL[ww][ln];
        ltot = s;
    }
    const float linv = 1.f / ltot;
#pragma unroll
    for (int n = 0; n < NT; n++) {
#pragma unroll
        for (int r = 0; r < 4; r++) {
            float invr = __shfl(linv, (g << 2) + r);
            float v = accF[n][r] * invr;
            int row = i0 + g * 4 + r;
            int col = n * 16 + ln;
            if (EPI == 1) v += xres[(size_t)row * D + col];
            if (EPI >= 1) v = v > 0.f ? v : (__expf(v) - 1.f);
            out[(size_t)row * ncols + hd * D + col] = v;
        }
    }
}

// ---------------- final: log_softmax(elu(h3)) over 16 cols ----------------
__global__ void final_kernel(const float* __restrict__ h3, float* __restrict__ out) {
    int i = blockIdx.x * 256 + threadIdx.x;
    if (i >= NN) return;
    float v[OUTD];
    float mx = -1e30f;
#pragma unroll
    for (int k = 0; k < OUTD; k++) {
        float e = h3[(size_t)i * OUTD + k];
        e = e > 0.f ? e : (__expf(e) - 1.f);
        v[k] = e;
        mx = fmaxf(mx, e);
    }
    float s = 0.f;
#pragma unroll
    for (int k = 0; k < OUTD; k++) s += __expf(v[k] - mx);
    float ls = logf(s);
#pragma unroll
    for (int k = 0; k < OUTD; k++) out[(size_t)i * OUTD + k] = v[k] - mx - ls;
}

extern "C" void kernel_launch(void* const* d_in, const int* in_sizes, int n_in,
                              void* d_out, int out_size, void* d_ws, size_t ws_size,
                              hipStream_t stream) {
    const float* x = (const float*)d_in[0];
    const int* adj = (const int*)d_in[1];
    const float* W_in = (const float*)d_in[2];
    const float* a_in = (const float*)d_in[3];
    const float* W_hid = (const float*)d_in[4];
    const float* a_hid = (const float*)d_in[5];
    const float* W_out = (const float*)d_in[6];
    const float* a_out = (const float*)d_in[7];
    float* out = (float*)d_out;

    char* w = (char*)d_ws;
    unsigned int* mb = (unsigned int*)w;  w += (size_t)NN * MASKW * 4;            // 2 MB
    ushort* hT = (ushort*)w;              w += (size_t)HH * NN * FF * 2;          // 4 MB (L1 max)
    ushort* xb16 = (ushort*)w;            w += (size_t)NN * FF * 2;               // 1 MB
    ushort* cat1b = (ushort*)w;           w += (size_t)NN * (HH * FF) * 2;        // 4 MB
    ushort* cat2b = (ushort*)w;           w += (size_t)NN * (HH * HIDD) * 2;      // 2 MB
    ushort* wt1 = (ushort*)w;             w += 65536 * 2;
    ushort* wt2 = (ushort*)w;             w += 131072 * 2;
    ushort* wt3 = (ushort*)w;             w += 4096 * 2;
    float* vbuf = (float*)w;              w += 5632 * 4;
    float* f1 = (float*)w;                w += (size_t)HH * NN * 4;
    float* f2 = (float*)w;                w += (size_t)HH * NN * 4;
    float* gm = (float*)w;                w += 256;
    float* h3 = (float*)w;                w += (size_t)NN * OUTD * 4;             // 256 KB
    size_t base_used = (size_t)(w - (char*)d_ws);

    // j-split factor chosen from available workspace (constant across calls)
    int JS = 0;
    float* pacc = (float*)w;
    float* plsum = nullptr;
    {
        size_t per_js = (size_t)HH * NN * FF * 4;
        size_t ls_per_js = (size_t)HH * NN * 4;
        for (int cand = 4; cand >= 1; cand >>= 1) {
            size_t need = base_used + (size_t)cand * per_js + (size_t)(2 * cand) * ls_per_js + 1024;
            if (ws_size >= need) { JS = cand; break; }
        }
        if (JS) plsum = (float*)((char*)pacc + (size_t)JS * per_js);
    }
    const int JS2 = 2 * JS;

    // ---- prep: mask, bf16 x, W^T bf16, v = W.a ----
    hipLaunchKernelGGL(pack_mask_kernel, dim3(NN * NN / 256), dim3(256), 0, stream, adj, mb);
    hipLaunchKernelGGL(cvt_kernel, dim3(NN * FF / 1024), dim3(256), 0, stream, x, xb16);
    hipLaunchKernelGGL(wtprep_kernel, dim3(784), dim3(256), 0, stream,
                       W_in, W_hid, W_out, wt1, wt2, wt3);
    hipLaunchKernelGGL(vprep_kernel, dim3(22), dim3(256), 0, stream,
                       W_in, a_in, W_hid, a_hid, W_out, a_out, vbuf);

    // ---- layer 1: K=128, D=128, 4 heads, residual+elu, concat -> cat1b[N,512] bf16
    hipLaunchKernelGGL((proj_mfma_kernel<FF, FF, 0>), dim3(NN / 16, HH), dim3(256), 0, stream,
                       xb16, wt1, hT);
    hipLaunchKernelGGL((score_kernel<float, FF, HH>), dim3(HH * NN / 4), dim3(256), 0, stream,
                       x, vbuf, f1, f2);
    hipLaunchKernelGGL(gmax_kernel, dim3(HH), dim3(256), 0, stream, f2, gm);
    if (JS) {
        hipLaunchKernelGGL((agg3_kernel<FF>), dim3(NN / 64, JS, HH), dim3(256), 0, stream,
                           hT, f1, f2, gm, mb, pacc, plsum);
        hipLaunchKernelGGL((combine_kernel<FF, 1>), dim3(NN * FF / 1024, HH), dim3(256), 0, stream,
                           pacc, plsum, x, cat1b, HH * FF, JS);
    } else {
        hipLaunchKernelGGL((agg2_kernel<FF, 1>), dim3(NN / 64, 1, HH), dim3(256), 0, stream,
                           hT, f1, f2, gm, mb, x, cat1b, HH * FF);
    }

    // ---- layer 2: K=512, D=64, 4 heads, elu, concat -> cat2b[N,256] bf16
    hipLaunchKernelGGL((proj_mfma_kernel<HH * FF, HIDD, 0>), dim3(NN / 16, HH), dim3(256), 0, stream,
                       cat1b, wt2, hT);
    hipLaunchKernelGGL((score_kernel<ushort, HH * FF, HH>), dim3(HH * NN / 4), dim3(256), 0, stream,
                       cat1b, vbuf + 1024, f1, f2);
    hipLaunchKernelGGL(gmax_kernel, dim3(HH), dim3(256), 0, stream, f2, gm);
    if (JS) {
        hipLaunchKernelGGL((agg3_kernel<HIDD>), dim3(NN / 64, JS2, HH), dim3(256), 0, stream,
                           hT, f1, f2, gm, mb, pacc, plsum);
        hipLaunchKernelGGL((combine_kernel<HIDD, 2>), dim3(NN * HIDD / 1024, HH), dim3(256), 0, stream,
                           pacc, plsum, (const float*)nullptr, cat2b, HH * HIDD, JS2);
    } else {
        hipLaunchKernelGGL((agg2_kernel<HIDD, 2>), dim3(NN / 64, 1, HH), dim3(256), 0, stream,
                           hT, f1, f2, gm, mb, (const float*)nullptr, cat2b, HH * HIDD);
    }

    // ---- layer 3: K=256, D=16, 1 head, no elu inside -> h3[N,16] fp32
    hipLaunchKernelGGL((proj_mfma_kernel<HH * HIDD, OUTD, 1>), dim3(NN / 64, 1), dim3(256), 0, stream,
                       cat2b, wt3, hT);
    hipLaunchKernelGGL((score_kernel<ushort, HH * HIDD, 1>), dim3(NN / 4), dim3(256), 0, stream,
                       cat2b, vbuf + 5120, f1, f2);
    hipLaunchKernelGGL(gmax_kernel, dim3(1), dim3(256), 0, stream, f2, gm);
    hipLaunchKernelGGL((agg_mfma_kernel<OUTD, 0, 4>), dim3(NN / 16, 1, 1), dim3(256), 0, stream,
                       hT, f1, f2, gm, mb, (const float*)nullptr, h3, OUTD);

    hipLaunchKernelGGL(final_kernel, dim3(NN / 256), dim3(256), 0, stream, h3, out);
}